// Round 2
// baseline (1401.709 us; speedup 1.0000x reference)
//
#include <hip/hip_runtime.h>

#define LB __launch_bounds__(256)

// ---------------------------------------------------------------------------
// B=2 N=256 C=256 HF=WF=64 ROI=15 (225) HID=256 HEADS=8 Dh=32 DEPTH=3
// FFN=1024 NQ=16 -> seqs S=512, target rows MT=8192
// Linearity trick: bilinear sample() commutes with channel-space linear maps:
//   K = sample(imgP @ Wk^T) + (proj_b @ Wk^T + bk)   (invalid -> sample=0)
// so `mem` (115200x256) is never materialized. Workspace ~92 MB.
// ---------------------------------------------------------------------------

// ---------- mask dtype detect + expand to int[512] -------------------------
__global__ void k_mask(const unsigned char* __restrict__ m, int* __restrict__ valid)
{
    __shared__ int flag;   // nonzero -> byte(bool) layout
    if (threadIdx.x == 0) flag = 0;
    __syncthreads();
    int loc = 0;
    for (int off = threadIdx.x; off < 512; off += 256)
        if ((off & 3) != 0 && m[off] != 0) loc = 1;
    if (loc) atomicOr(&flag, 1);
    __syncthreads();
    const bool bytelay = (flag != 0);
    for (int s = threadIdx.x; s < 512; s += 256)
        valid[s] = bytelay ? (int)(m[s] != 0) : (int)(((const int*)m)[s] != 0);
}

// ---------- transpose image (B,C,64,64) -> (B, 4096, C) --------------------
__global__ LB void k_transpose(const float* __restrict__ img, float* __restrict__ imgT)
{
    __shared__ float tile[64][65];
    const int b  = blockIdx.z;
    const int c0 = blockIdx.y * 64;
    const int p0 = blockIdx.x * 64;
    const int t  = threadIdx.x;
    const int tr = t >> 6;      // 0..3
    const int tc = t & 63;
#pragma unroll
    for (int p = 0; p < 16; ++p) {
        const int i = p * 4 + tr;
        tile[i][tc] = img[((size_t)(b * 256 + c0 + i)) * 4096 + p0 + tc];
    }
    __syncthreads();
#pragma unroll
    for (int p = 0; p < 16; ++p) {
        const int jj = p * 4 + tr;
        imgT[((size_t)(b * 4096 + p0 + jj)) * 256 + c0 + tc] = tile[tc][jj];
    }
}

// ---------- generic tiled fp32 GEMM: C[M,N] = A[M,K] @ W[N,K]^T (+bias) ----
__global__ LB void gemm_bias(const float* __restrict__ A,
                             const float* __restrict__ W,
                             const float* __restrict__ bias,
                             float* __restrict__ C,
                             int M, int N, int K, int relu)
{
    __shared__ float As[16][68];
    __shared__ float Ws[16][68];
    const int bn = blockIdx.x * 64;
    const int bm = blockIdx.y * 64;
    const int t  = threadIdx.x;
    const int tx = t & 15;
    const int ty = t >> 4;
    const int lrow = t >> 2;            // 0..63
    const int lk   = (t & 3) * 4;       // 0,4,8,12

    float acc[4][4] = {};
    for (int k0 = 0; k0 < K; k0 += 16) {
        const float4 a4 = *(const float4*)(A + (size_t)(bm + lrow) * K + k0 + lk);
        const float4 w4 = *(const float4*)(W + (size_t)(bn + lrow) * K + k0 + lk);
        As[lk + 0][lrow] = a4.x; As[lk + 1][lrow] = a4.y;
        As[lk + 2][lrow] = a4.z; As[lk + 3][lrow] = a4.w;
        Ws[lk + 0][lrow] = w4.x; Ws[lk + 1][lrow] = w4.y;
        Ws[lk + 2][lrow] = w4.z; Ws[lk + 3][lrow] = w4.w;
        __syncthreads();
#pragma unroll
        for (int k = 0; k < 16; ++k) {
            const float4 a = *(const float4*)(&As[k][ty * 4]);
            const float4 w = *(const float4*)(&Ws[k][tx * 4]);
            const float av[4] = {a.x, a.y, a.z, a.w};
            const float wv[4] = {w.x, w.y, w.z, w.w};
#pragma unroll
            for (int ii = 0; ii < 4; ++ii)
#pragma unroll
                for (int jj = 0; jj < 4; ++jj)
                    acc[ii][jj] = fmaf(av[ii], wv[jj], acc[ii][jj]);
        }
        __syncthreads();
    }

    float4 bias4 = make_float4(0.f, 0.f, 0.f, 0.f);
    if (bias) bias4 = *(const float4*)(bias + bn + tx * 4);
#pragma unroll
    for (int ii = 0; ii < 4; ++ii) {
        float4 o;
        o.x = acc[ii][0] + bias4.x;
        o.y = acc[ii][1] + bias4.y;
        o.z = acc[ii][2] + bias4.z;
        o.w = acc[ii][3] + bias4.w;
        if (relu) {
            o.x = fmaxf(o.x, 0.0f); o.y = fmaxf(o.y, 0.0f);
            o.z = fmaxf(o.z, 0.0f); o.w = fmaxf(o.w, 0.0f);
        }
        *(float4*)(C + (size_t)(bm + ty * 4 + ii) * N + bn + tx * 4) = o;
    }
}

// ---------- combined constants: ckv[0:256]=pb@Wk^T+kb, ckv[256:512]=pb@Wv^T+vb
__global__ void k_bias_combo(const float* __restrict__ pb,
                             const float* __restrict__ Wk, const float* __restrict__ kb,
                             const float* __restrict__ Wv, const float* __restrict__ vb,
                             float* __restrict__ ckv)
{
    const int o = threadIdx.x;  // 256
    float a = 0.f, c = 0.f;
    for (int cc = 0; cc < 256; cc += 4) {
        const float4 p4 = *(const float4*)(pb + cc);
        const float4 k4 = *(const float4*)(Wk + (size_t)o * 256 + cc);
        const float4 v4 = *(const float4*)(Wv + (size_t)o * 256 + cc);
        a += p4.x * k4.x + p4.y * k4.y + p4.z * k4.z + p4.w * k4.w;
        c += p4.x * v4.x + p4.y * v4.y + p4.z * v4.z + p4.w * v4.w;
    }
    ckv[o]       = a + kb[o];
    ckv[256 + o] = c + vb[o];
}

// ---------- init tgt: broadcast query_embed over 512 sequences -------------
__global__ LB void k_init_tgt(float* __restrict__ tgt, const float* __restrict__ qe)
{
    const int e = blockIdx.x * 256 + threadIdx.x;
    const int c = e & 255;
    const int row = e >> 8;
    const int i = row & 15;
    tgt[e] = qe[(i << 8) | c];
}

// ---------- self attention: per (seq, head), 16 q x 16 k, Dh=32 ------------
__global__ LB void k_self_attn(const float* __restrict__ QKV, float* __restrict__ O)
{
    const int blk = blockIdx.x;
    const int s = blk >> 3, h = blk & 7;
    __shared__ float q_s[16][36], k_s[16][36], v_s[16][36];
    __shared__ float e_s[16][17];
    __shared__ float rsum[16];
    const int t = threadIdx.x;
    const int i = t >> 4, j = t & 15;

    const float* basep = QKV + (size_t)(s * 16 + i) * 768 + h * 32;
    q_s[i][j]      = basep[j];
    q_s[i][j + 16] = basep[j + 16];
    k_s[i][j]      = basep[256 + j];
    k_s[i][j + 16] = basep[256 + j + 16];
    v_s[i][j]      = basep[512 + j];
    v_s[i][j + 16] = basep[512 + j + 16];
    __syncthreads();

    float acc = 0.0f;
#pragma unroll
    for (int d = 0; d < 32; d += 4) {
        const float4 q4 = *(const float4*)(&q_s[i][d]);
        const float4 k4 = *(const float4*)(&k_s[j][d]);
        acc += q4.x * k4.x + q4.y * k4.y + q4.z * k4.z + q4.w * k4.w;
    }
    const float sc = acc * 0.17677669529663687f;
    e_s[i][j] = sc;
    __syncthreads();
    float mx = e_s[i][0];
#pragma unroll
    for (int x = 1; x < 16; ++x) mx = fmaxf(mx, e_s[i][x]);
    const float e = __expf(sc - mx);
    __syncthreads();
    e_s[i][j] = e;
    __syncthreads();
    if (j == 0) {
        float sm = 0.0f;
#pragma unroll
        for (int x = 0; x < 16; ++x) sm += e_s[i][x];
        rsum[i] = sm;
    }
    __syncthreads();

    const int oi = t >> 5;
    const int d  = t & 31;
#pragma unroll
    for (int pass = 0; pass < 2; ++pass) {
        const int r = oi + pass * 8;
        float o = 0.0f;
#pragma unroll
        for (int x = 0; x < 16; ++x) o += e_s[r][x] * v_s[x][d];
        O[(size_t)(s * 16 + r) * 256 + h * 32 + d] = o / rsum[r];
    }
}

// ---------- fused cross attention with on-the-fly ROI sampling -------------
__global__ LB void k_cross_attn(const float* __restrict__ Q,
                                const float* __restrict__ imgK,
                                const float* __restrict__ imgV,
                                const float* __restrict__ ckv,
                                const int* __restrict__ valid,
                                const float* __restrict__ kps,
                                float* __restrict__ O)
{
    const int blk = blockIdx.x;
    const int s = blk >> 3, h = blk & 7;
    const int b = s >> 8, n = s & 255;
    __shared__ float q_s[16][36];
    __shared__ int   t_idx[225][4];
    __shared__ float t_w[225][4];
    __shared__ float kv_s[225][36];
    __shared__ float s_s[16][225];
    __shared__ float red[16][17];
    __shared__ float rowm[16], rowsum[16];
    const int t = threadIdx.x;
    const int i = t >> 4, jj = t & 15;

    q_s[i][jj]      = Q[(size_t)(s * 16 + i) * 256 + h * 32 + jj];
    q_s[i][jj + 16] = Q[(size_t)(s * 16 + i) * 256 + h * 32 + jj + 16];

    if (t < 225) {
        const float kpy = kps[(b * 256 + n) * 2 + 0];
        const float kpx = kps[(b * 256 + n) * 2 + 1];
        const int iy = t / 15, ix = t - iy * 15;
        const float gy = rintf(kpy) + (float)(iy - 7);
        const float gx = rintf(kpx) + (float)(ix - 7);
        const float gxn = gx / 511.0f * 2.0f - 1.0f;
        const float gyn = gy / 511.0f * 2.0f - 1.0f;
        const bool inval = (gxn < -1.f) || (gyn < -1.f) || (gxn > 1.f) || (gyn > 1.f);
        const float x = ((gxn + 1.f) * 64.f - 1.f) * 0.5f;
        const float y = ((gyn + 1.f) * 64.f - 1.f) * 0.5f;
        const float x0f = floorf(x), y0f = floorf(y);
        const float wx = x - x0f, wy = y - y0f;
        const int x0 = (int)x0f, y0 = (int)y0f;
#pragma unroll
        for (int tt = 0; tt < 4; ++tt) {
            const int dy = tt >> 1, dx = tt & 1;
            const int yi = y0 + dy, xi = x0 + dx;
            const bool ok = (yi >= 0) && (yi < 64) && (xi >= 0) && (xi < 64) && !inval;
            const float w = (dy ? wy : 1.f - wy) * (dx ? wx : 1.f - wx);
            t_idx[t][tt] = ok ? (yi * 64 + xi) : 0;
            t_w[t][tt]   = ok ? w : 0.f;
        }
    }
    const bool vld = valid[s] != 0;
    __syncthreads();

    // ---- sample K (+ck) into kv_s ----
    {
        const int tp = t >> 3;          // 0..31
        const int ld = (t & 7) * 4;     // 0..28
        const float* baseI = imgK + (size_t)b * 4096 * 256 + h * 32 + ld;
        const float4 cc = *(const float4*)(ckv + h * 32 + ld);
        for (int p0 = 0; p0 < 225; p0 += 32) {
            const int p = p0 + tp;
            if (p < 225) {
                float4 acc = cc;
#pragma unroll
                for (int tt = 0; tt < 4; ++tt) {
                    const float w = t_w[p][tt];
                    const float4 v = *(const float4*)(baseI + (size_t)t_idx[p][tt] * 256);
                    acc.x += w * v.x; acc.y += w * v.y; acc.z += w * v.z; acc.w += w * v.w;
                }
                *(float4*)(&kv_s[p][ld]) = acc;
            }
        }
    }
    __syncthreads();

    // ---- scores ----
    for (int j = jj; j < 225; j += 16) {
        float acc = 0.0f;
#pragma unroll
        for (int d = 0; d < 32; d += 4) {
            const float4 q4 = *(const float4*)(&q_s[i][d]);
            const float4 k4 = *(const float4*)(&kv_s[j][d]);
            acc += q4.x * k4.x + q4.y * k4.y + q4.z * k4.z + q4.w * k4.w;
        }
        float sv = acc * 0.17677669529663687f;
        if (!vld && j > 0) sv = -1e30f;
        s_s[i][j] = sv;
    }
    __syncthreads();

    // ---- softmax over 225 per row ----
    float pm = -1e30f;
    for (int j = jj; j < 225; j += 16) pm = fmaxf(pm, s_s[i][j]);
    red[i][jj] = pm;
    __syncthreads();
    if (t < 16) {
        float m = red[t][0];
#pragma unroll
        for (int x = 1; x < 16; ++x) m = fmaxf(m, red[t][x]);
        rowm[t] = m;
    }
    __syncthreads();
    const float mx = rowm[i];
    float ps = 0.0f;
    for (int j = jj; j < 225; j += 16) {
        const float e = __expf(s_s[i][j] - mx);
        s_s[i][j] = e;
        ps += e;
    }
    red[i][jj] = ps;
    __syncthreads();
    if (t < 16) {
        float sm = 0.0f;
#pragma unroll
        for (int x = 0; x < 16; ++x) sm += red[t][x];
        rowsum[t] = sm;
    }
    __syncthreads();

    // ---- sample V (+cv) into kv_s (overwrite) ----
    {
        const int tp = t >> 3;
        const int ld = (t & 7) * 4;
        const float* baseI = imgV + (size_t)b * 4096 * 256 + h * 32 + ld;
        const float4 cc = *(const float4*)(ckv + 256 + h * 32 + ld);
        for (int p0 = 0; p0 < 225; p0 += 32) {
            const int p = p0 + tp;
            if (p < 225) {
                float4 acc = cc;
#pragma unroll
                for (int tt = 0; tt < 4; ++tt) {
                    const float w = t_w[p][tt];
                    const float4 v = *(const float4*)(baseI + (size_t)t_idx[p][tt] * 256);
                    acc.x += w * v.x; acc.y += w * v.y; acc.z += w * v.z; acc.w += w * v.w;
                }
                *(float4*)(&kv_s[p][ld]) = acc;
            }
        }
    }
    __syncthreads();

    // ---- PV ----
    const int d0 = jj * 2;   // 0..30
    float o0 = 0.0f, o1 = 0.0f;
    for (int j = 0; j < 225; ++j) {
        const float p = s_s[i][j];
        o0 = fmaf(p, kv_s[j][d0], o0);
        o1 = fmaf(p, kv_s[j][d0 + 1], o1);
    }
    const float inv = 1.0f / rowsum[i];
    float2 o2; o2.x = o0 * inv; o2.y = o1 * inv;
    *(float2*)(O + (size_t)(s * 16 + i) * 256 + h * 32 + d0) = o2;
}

// ---------- residual add + LayerNorm (in-place on X), rows of 256 ----------
__global__ LB void k_add_ln(float* __restrict__ X, const float* __restrict__ D,
                            const float* __restrict__ w, const float* __restrict__ b)
{
    const int row  = blockIdx.x * 4 + (threadIdx.x >> 6);
    const int lane = threadIdx.x & 63;
    float4 x = ((const float4*)(X + (size_t)row * 256))[lane];
    const float4 d = ((const float4*)(D + (size_t)row * 256))[lane];
    x.x += d.x; x.y += d.y; x.z += d.z; x.w += d.w;
    float s = x.x + x.y + x.z + x.w;
#pragma unroll
    for (int m = 1; m < 64; m <<= 1) s += __shfl_xor(s, m);
    const float mu = s * (1.0f / 256.0f);
    const float4 c = make_float4(x.x - mu, x.y - mu, x.z - mu, x.w - mu);
    float q = c.x * c.x + c.y * c.y + c.z * c.z + c.w * c.w;
#pragma unroll
    for (int m = 1; m < 64; m <<= 1) q += __shfl_xor(q, m);
    const float inv = 1.0f / sqrtf(q * (1.0f / 256.0f) + 1e-5f);
    const float4 w4 = ((const float4*)w)[lane];
    const float4 b4 = ((const float4*)b)[lane];
    float4 o;
    o.x = c.x * inv * w4.x + b4.x;
    o.y = c.y * inv * w4.y + b4.y;
    o.z = c.z * inv * w4.z + b4.z;
    o.w = c.w * inv * w4.w + b4.w;
    ((float4*)(X + (size_t)row * 256))[lane] = o;
}

// ---------- output head: (8192,256) @ (4,256)^T + b ------------------------
__global__ LB void k_out(const float* __restrict__ X, const float* __restrict__ W,
                         const float* __restrict__ bias, float* __restrict__ O)
{
    __shared__ float w_s[4][260];
    const int t = threadIdx.x;
    for (int e = t; e < 1024; e += 256) w_s[e >> 8][e & 255] = W[e];
    __syncthreads();
    const int row = blockIdx.x * 64 + (t >> 2);
    const int j = t & 3;
    const float4* xr = (const float4*)(X + (size_t)row * 256);
    float acc = 0.0f;
#pragma unroll
    for (int k4 = 0; k4 < 64; ++k4) {
        const float4 x = xr[k4];
        acc += x.x * w_s[j][k4 * 4]     + x.y * w_s[j][k4 * 4 + 1]
             + x.z * w_s[j][k4 * 4 + 2] + x.w * w_s[j][k4 * 4 + 3];
    }
    O[(size_t)row * 4 + j] = acc + bias[j];
}

// ---------------------------------------------------------------------------
extern "C" void kernel_launch(void* const* d_in, const int* in_sizes, int n_in,
                              void* d_out, int out_size, void* d_ws, size_t ws_size,
                              hipStream_t stream)
{
    const float* img          = (const float*)d_in[0];
    const float* kps          = (const float*)d_in[1];
    const unsigned char* vmsk = (const unsigned char*)d_in[2];
    const float* proj_w       = (const float*)d_in[3];
    const float* proj_b       = (const float*)d_in[4];
    const float* query_embed  = (const float*)d_in[5];
    const float* self_qkv_w   = (const float*)d_in[6];
    const float* self_qkv_b   = (const float*)d_in[7];
    const float* self_out_w   = (const float*)d_in[8];
    const float* self_out_b   = (const float*)d_in[9];
    const float* cross_qkv_w  = (const float*)d_in[10];
    const float* cross_qkv_b  = (const float*)d_in[11];
    const float* cross_out_w  = (const float*)d_in[12];
    const float* cross_out_b  = (const float*)d_in[13];
    const float* ffn1_w       = (const float*)d_in[14];
    const float* ffn1_b       = (const float*)d_in[15];
    const float* ffn2_w       = (const float*)d_in[16];
    const float* ffn2_b       = (const float*)d_in[17];
    const float* ln1_w        = (const float*)d_in[18];
    const float* ln1_b        = (const float*)d_in[19];
    const float* ln2_w        = (const float*)d_in[20];
    const float* ln2_b        = (const float*)d_in[21];
    const float* ln3_w        = (const float*)d_in[22];
    const float* ln3_b        = (const float*)d_in[23];
    const float* out_w        = (const float*)d_in[24];
    const float* out_b        = (const float*)d_in[25];
    float* out = (float*)d_out;

    // workspace layout (floats) — total ~23.07M floats = 92.3 MB
    float* ws   = (float*)d_ws;
    float* imgT = ws;                   // 2,097,152
    float* imgP = imgT + 2097152;       // 2,097,152
    float* tgt  = imgP + 2097152;       // 2,097,152
    float* Abuf = tgt  + 2097152;       // 2,097,152 (attention outputs)
    float* Pbuf = Abuf + 2097152;       // 2,097,152 (proj outputs)
    float* Kb   = Pbuf + 2097152;       // 2,097,152 (imgK)
    float* Vb   = Kb   + 2097152;       // 2,097,152 (imgV)
    float* Sbuf = Vb   + 2097152;       // 8,388,608 (qkv / ffn hidden / cross-q)
    float* ckv  = Sbuf + 8388608;       // 512
    int*   valid = (int*)(ckv + 512);   // 512 ints

    k_mask<<<1, 256, 0, stream>>>(vmsk, valid);
    k_transpose<<<dim3(64, 4, 2), 256, 0, stream>>>(img, imgT);
    gemm_bias<<<dim3(4, 128), 256, 0, stream>>>(imgT, proj_w, nullptr, imgP,
                                                8192, 256, 256, 0);
    k_init_tgt<<<8192, 256, 0, stream>>>(tgt, query_embed);

    for (int l = 0; l < 3; ++l) {
        const float* sqkv_w = self_qkv_w + (size_t)l * 768 * 256;
        const float* sqkv_b = self_qkv_b + (size_t)l * 768;
        const float* cqkv_w = cross_qkv_w + (size_t)l * 768 * 256;
        const float* cqkv_b = cross_qkv_b + (size_t)l * 768;

        // ---- self attention ----
        gemm_bias<<<dim3(12, 128), 256, 0, stream>>>(tgt, sqkv_w, sqkv_b, Sbuf,
                                                     8192, 768, 256, 0);
        k_self_attn<<<4096, 256, 0, stream>>>(Sbuf, Abuf);
        gemm_bias<<<dim3(4, 128), 256, 0, stream>>>(Abuf,
            self_out_w + (size_t)l * 256 * 256, self_out_b + (size_t)l * 256,
            Pbuf, 8192, 256, 256, 0);
        k_add_ln<<<2048, 256, 0, stream>>>(tgt, Pbuf,
            ln1_w + (size_t)l * 256, ln1_b + (size_t)l * 256);

        // ---- cross attention ----
        gemm_bias<<<dim3(4, 128), 256, 0, stream>>>(tgt, cqkv_w, cqkv_b, Sbuf,
                                                    8192, 256, 256, 0);
        gemm_bias<<<dim3(4, 128), 256, 0, stream>>>(imgP, cqkv_w + 256 * 256,
            nullptr, Kb, 8192, 256, 256, 0);
        gemm_bias<<<dim3(4, 128), 256, 0, stream>>>(imgP, cqkv_w + 512 * 256,
            nullptr, Vb, 8192, 256, 256, 0);
        k_bias_combo<<<1, 256, 0, stream>>>(proj_b,
            cqkv_w + 256 * 256, cqkv_b + 256,
            cqkv_w + 512 * 256, cqkv_b + 512, ckv);
        k_cross_attn<<<4096, 256, 0, stream>>>(Sbuf, Kb, Vb, ckv, valid, kps, Abuf);
        gemm_bias<<<dim3(4, 128), 256, 0, stream>>>(Abuf,
            cross_out_w + (size_t)l * 256 * 256, cross_out_b + (size_t)l * 256,
            Pbuf, 8192, 256, 256, 0);
        k_add_ln<<<2048, 256, 0, stream>>>(tgt, Pbuf,
            ln2_w + (size_t)l * 256, ln2_b + (size_t)l * 256);

        // ---- FFN ----
        gemm_bias<<<dim3(16, 128), 256, 0, stream>>>(tgt,
            ffn1_w + (size_t)l * 1024 * 256, ffn1_b + (size_t)l * 1024,
            Sbuf, 8192, 1024, 256, 1);
        gemm_bias<<<dim3(4, 128), 256, 0, stream>>>(Sbuf,
            ffn2_w + (size_t)l * 256 * 1024, ffn2_b + (size_t)l * 256,
            Pbuf, 8192, 256, 1024, 0);
        k_add_ln<<<2048, 256, 0, stream>>>(tgt, Pbuf,
            ln3_w + (size_t)l * 256, ln3_b + (size_t)l * 256);
    }

    k_out<<<128, 256, 0, stream>>>(tgt, out_w, out_b, out);
}

// Round 4
// 638.957 us; speedup vs baseline: 2.1937x; 2.1937x over previous
//
#include <hip/hip_runtime.h>
#include <hip/hip_fp16.h>

#define LB __launch_bounds__(256)

typedef unsigned short u16;
typedef unsigned int   u32;
typedef __attribute__((ext_vector_type(8))) short bf16x8;   // 8 bf16 (4 VGPRs)
typedef __attribute__((ext_vector_type(4))) float f32x4;
typedef __attribute__((ext_vector_type(8))) u16  u16x8;

__device__ __forceinline__ u16 f2b(float f) {
    u32 u = __float_as_uint(f);
    u32 r = (u + 0x7fffu + ((u >> 16) & 1u)) >> 16;
    return (u16)r;
}
__device__ __forceinline__ float b2f(u16 h) {
    return __uint_as_float((u32)h << 16);
}

// ---------------------------------------------------------------------------
// B=2 N=256 C=256 HF=WF=64 ROI=15(225) HID=256 HEADS=8 Dh=32 DEPTH=3 FFN=1024
// NQ=16 -> seqs S=512, MT=8192. Linearity: K = sample(imgP@Wk^T) + ckv.
// ---------------------------------------------------------------------------

// ---------- mask dtype detect + expand to int[512] -------------------------
__global__ void k_mask(const unsigned char* __restrict__ m, int* __restrict__ valid)
{
    __shared__ int flag;
    if (threadIdx.x == 0) flag = 0;
    __syncthreads();
    int loc = 0;
    for (int off = threadIdx.x; off < 512; off += 256)
        if ((off & 3) != 0 && m[off] != 0) loc = 1;
    if (loc) atomicOr(&flag, 1);
    __syncthreads();
    const bool bytelay = (flag != 0);
    for (int s = threadIdx.x; s < 512; s += 256)
        valid[s] = bytelay ? (int)(m[s] != 0) : (int)(((const int*)m)[s] != 0);
}

// ---------- weights fp32 -> bf16 arena -------------------------------------
__global__ LB void k_wconv(const float* __restrict__ s0, const float* __restrict__ s1,
                           const float* __restrict__ s2, const float* __restrict__ s3,
                           const float* __restrict__ s4, const float* __restrict__ s5,
                           const float* __restrict__ s6, u16* __restrict__ dst)
{
    const int e = blockIdx.x * 256 + threadIdx.x;
    if (e >= 3211264) return;
    float v;
    int i = e;
    if (i < 65536) v = s0[i];
    else if ((i -= 65536) < 589824) v = s1[i];
    else if ((i -= 589824) < 196608) v = s2[i];
    else if ((i -= 196608) < 589824) v = s3[i];
    else if ((i -= 589824) < 196608) v = s4[i];
    else if ((i -= 196608) < 786432) v = s5[i];
    else { i -= 786432; v = s6[i]; }
    dst[e] = f2b(v);
}

// ---------- transpose image (B,C,64,64) -> (B,4096,C) bf16 -----------------
__global__ LB void k_transpose(const float* __restrict__ img, u16* __restrict__ imgTb)
{
    __shared__ float tile[64][65];
    const int b  = blockIdx.z;
    const int c0 = blockIdx.y * 64;
    const int p0 = blockIdx.x * 64;
    const int t  = threadIdx.x;
    const int tr = t >> 6, tc = t & 63;
#pragma unroll
    for (int p = 0; p < 16; ++p) {
        const int i = p * 4 + tr;
        tile[i][tc] = img[((size_t)(b * 256 + c0 + i)) * 4096 + p0 + tc];
    }
    __syncthreads();
#pragma unroll
    for (int p = 0; p < 16; ++p) {
        const int jj = p * 4 + tr;
        imgTb[((size_t)(b * 4096 + p0 + jj)) * 256 + c0 + tc] = f2b(tile[tc][jj]);
    }
}

// ---------- bf16 MFMA GEMM: C[M,N] = A[M,K](bf16) @ W[N,K](bf16)^T + bias --
// BM in {64,128}, BN=128, BK=64, 4 waves (2x2), 16x16x32 MFMA.
// LDS rows are 128B; XOR swizzle slot^=(row&7) on BOTH global-src and ds_read.
template<int BM>
__global__ LB void gemm_mfma(const u16* __restrict__ A, const u16* __restrict__ W,
                             const float* __restrict__ bias,
                             float* __restrict__ Cf, u16* __restrict__ Cb,
                             int M, int N, int K, int relu)
{
    constexpr int BN = 128;
    __shared__ u16 lds[2][(BM + BN) * 64];
    const int t = threadIdx.x;
    const int wid = t >> 6, lane = t & 63;
    const int bm = blockIdx.y * BM, bn = blockIdx.x * BN;
    const int KT = K >> 6;

    auto stage = [&](int buf, int kt) {
        const int k0 = kt * 64;
        const int rr = t >> 3;          // 0..31 (8 rows per wave)
        const int u  = t & 7;
#pragma unroll
        for (int q = 0; q < BM / 32; ++q) {
            const int r = q * 32 + rr;
            const u16* src = A + (size_t)(bm + r) * K + k0 + ((u ^ (r & 7)) << 3);
            __builtin_amdgcn_global_load_lds(
                (const __attribute__((address_space(1))) void*)src,
                (__attribute__((address_space(3))) void*)&lds[buf][q * 2048 + wid * 512],
                16, 0, 0);
        }
#pragma unroll
        for (int q = 0; q < 4; ++q) {
            const int r = q * 32 + rr;
            const u16* src = W + (size_t)(bn + r) * K + k0 + ((u ^ (r & 7)) << 3);
            __builtin_amdgcn_global_load_lds(
                (const __attribute__((address_space(1))) void*)src,
                (__attribute__((address_space(3))) void*)&lds[buf][BM * 64 + q * 2048 + wid * 512],
                16, 0, 0);
        }
    };

    const int wr = wid >> 1, wc = wid & 1;
    constexpr int MR = BM / 32;
    f32x4 acc[MR][4];
    const f32x4 z = {0.f, 0.f, 0.f, 0.f};
#pragma unroll
    for (int mi = 0; mi < MR; ++mi)
#pragma unroll
        for (int ni = 0; ni < 4; ++ni) acc[mi][ni] = z;

    const int r16 = lane & 15, kg = lane >> 4;

    stage(0, 0);
    int cur = 0;
    for (int kt = 0; kt < KT; ++kt) {
        asm volatile("s_waitcnt vmcnt(0)" ::: "memory");
        __syncthreads();
        if (kt + 1 < KT) stage(cur ^ 1, kt + 1);
        const u16* pA = lds[cur];
        const u16* pB = lds[cur] + BM * 64;
#pragma unroll
        for (int kk = 0; kk < 2; ++kk) {
            const int s = kk * 4 + kg;
            bf16x8 afr[MR], bfr[4];
#pragma unroll
            for (int mi = 0; mi < MR; ++mi) {
                const int r = wr * (BM / 2) + mi * 16 + r16;
                afr[mi] = *(const bf16x8*)(pA + r * 64 + ((s ^ (r & 7)) << 3));
            }
#pragma unroll
            for (int ni = 0; ni < 4; ++ni) {
                const int c = wc * 64 + ni * 16 + r16;
                bfr[ni] = *(const bf16x8*)(pB + c * 64 + ((s ^ (c & 7)) << 3));
            }
#pragma unroll
            for (int mi = 0; mi < MR; ++mi)
#pragma unroll
                for (int ni = 0; ni < 4; ++ni)
                    acc[mi][ni] = __builtin_amdgcn_mfma_f32_16x16x32_bf16(
                        afr[mi], bfr[ni], acc[mi][ni], 0, 0, 0);
        }
        cur ^= 1;
    }

#pragma unroll
    for (int mi = 0; mi < MR; ++mi) {
#pragma unroll
        for (int ni = 0; ni < 4; ++ni) {
            const int col = bn + wc * 64 + ni * 16 + r16;
            const float bs = bias ? bias[col] : 0.0f;
#pragma unroll
            for (int rg = 0; rg < 4; ++rg) {
                const int row = bm + wr * (BM / 2) + mi * 16 + kg * 4 + rg;
                float v = acc[mi][ni][rg] + bs;
                if (relu) v = fmaxf(v, 0.0f);
                if (Cf) Cf[(size_t)row * N + col] = v;
                if (Cb) Cb[(size_t)row * N + col] = f2b(v);
            }
        }
    }
}

// ---------- combined constants: ckv[0:256]=pb@Wk^T+kb, ckv[256:512]=pb@Wv^T+vb
__global__ void k_bias_combo(const float* __restrict__ pb,
                             const float* __restrict__ Wk, const float* __restrict__ kb,
                             const float* __restrict__ Wv, const float* __restrict__ vb,
                             float* __restrict__ ckv)
{
    const int o = threadIdx.x;
    float a = 0.f, c = 0.f;
    for (int cc = 0; cc < 256; cc += 4) {
        const float4 p4 = *(const float4*)(pb + cc);
        const float4 k4 = *(const float4*)(Wk + (size_t)o * 256 + cc);
        const float4 v4 = *(const float4*)(Wv + (size_t)o * 256 + cc);
        a += p4.x * k4.x + p4.y * k4.y + p4.z * k4.z + p4.w * k4.w;
        c += p4.x * v4.x + p4.y * v4.y + p4.z * v4.z + p4.w * v4.w;
    }
    ckv[o]       = a + kb[o];
    ckv[256 + o] = c + vb[o];
}

// ---------- init tgt (fp32 + bf16) -----------------------------------------
__global__ LB void k_init_tgt(float* __restrict__ tgt, u16* __restrict__ tgtb,
                              const float* __restrict__ qe)
{
    const int e = blockIdx.x * 256 + threadIdx.x;
    const int c = e & 255;
    const int row = e >> 8;
    const int i = row & 15;
    const float v = qe[(i << 8) | c];
    tgt[e] = v;
    tgtb[e] = f2b(v);
}

// ---------- self attention: per (seq, head), 16q x 16k, Dh=32; out bf16 ----
__global__ LB void k_self_attn(const float* __restrict__ QKV, u16* __restrict__ O)
{
    const int blk = blockIdx.x;
    const int s = blk >> 3, h = blk & 7;
    __shared__ float q_s[16][36], k_s[16][36], v_s[16][36];
    __shared__ float e_s[16][17];
    __shared__ float rsum[16];
    const int t = threadIdx.x;
    const int i = t >> 4, j = t & 15;

    const float* basep = QKV + (size_t)(s * 16 + i) * 768 + h * 32;
    q_s[i][j]      = basep[j];
    q_s[i][j + 16] = basep[j + 16];
    k_s[i][j]      = basep[256 + j];
    k_s[i][j + 16] = basep[256 + j + 16];
    v_s[i][j]      = basep[512 + j];
    v_s[i][j + 16] = basep[512 + j + 16];
    __syncthreads();

    float acc = 0.0f;
#pragma unroll
    for (int d = 0; d < 32; d += 4) {
        const float4 q4 = *(const float4*)(&q_s[i][d]);
        const float4 k4 = *(const float4*)(&k_s[j][d]);
        acc += q4.x * k4.x + q4.y * k4.y + q4.z * k4.z + q4.w * k4.w;
    }
    const float sc = acc * 0.17677669529663687f;
    e_s[i][j] = sc;
    __syncthreads();
    float mx = e_s[i][0];
#pragma unroll
    for (int x = 1; x < 16; ++x) mx = fmaxf(mx, e_s[i][x]);
    const float e = __expf(sc - mx);
    __syncthreads();
    e_s[i][j] = e;
    __syncthreads();
    if (j == 0) {
        float sm = 0.0f;
#pragma unroll
        for (int x = 0; x < 16; ++x) sm += e_s[i][x];
        rsum[i] = sm;
    }
    __syncthreads();

    const int oi = t >> 5;
    const int d  = t & 31;
#pragma unroll
    for (int pass = 0; pass < 2; ++pass) {
        const int r = oi + pass * 8;
        float o = 0.0f;
#pragma unroll
        for (int x = 0; x < 16; ++x) o += e_s[r][x] * v_s[x][d];
        O[(size_t)(s * 16 + r) * 256 + h * 32 + d] = f2b(o / rsum[r]);
    }
}

// ---------- fused cross attention with on-the-fly ROI sampling (bf16 KV) ---
__global__ LB void k_cross_attn(const float* __restrict__ Q,
                                const u16* __restrict__ KV,   // [B*4096][512] bf16
                                const float* __restrict__ ckv,
                                const int* __restrict__ valid,
                                const float* __restrict__ kps,
                                u16* __restrict__ O)
{
    const int blk = blockIdx.x;
    const int s = blk >> 3, h = blk & 7;
    const int b = s >> 8, n = s & 255;
    __shared__ float q_s[16][36];
    __shared__ u32   taps[225][4];       // idx<<16 | fp16 weight
    __shared__ u16   kv_s[225][40];      // bf16
    __shared__ float s_s[16][225];
    __shared__ float red[16][17];
    __shared__ float rowm[16], rowsum[16];
    const int t = threadIdx.x;
    const int i = t >> 4, jj = t & 15;

    q_s[i][jj]      = Q[(size_t)(s * 16 + i) * 256 + h * 32 + jj];
    q_s[i][jj + 16] = Q[(size_t)(s * 16 + i) * 256 + h * 32 + jj + 16];

    if (t < 225) {
        const float kpy = kps[(b * 256 + n) * 2 + 0];
        const float kpx = kps[(b * 256 + n) * 2 + 1];
        const int iy = t / 15, ix = t - iy * 15;
        const float gy = rintf(kpy) + (float)(iy - 7);
        const float gx = rintf(kpx) + (float)(ix - 7);
        const float gxn = gx / 511.0f * 2.0f - 1.0f;
        const float gyn = gy / 511.0f * 2.0f - 1.0f;
        const bool inval = (gxn < -1.f) || (gyn < -1.f) || (gxn > 1.f) || (gyn > 1.f);
        const float x = ((gxn + 1.f) * 64.f - 1.f) * 0.5f;
        const float y = ((gyn + 1.f) * 64.f - 1.f) * 0.5f;
        const float x0f = floorf(x), y0f = floorf(y);
        const float wx = x - x0f, wy = y - y0f;
        const int x0 = (int)x0f, y0 = (int)y0f;
#pragma unroll
        for (int tt = 0; tt < 4; ++tt) {
            const int dy = tt >> 1, dx = tt & 1;
            const int yi = y0 + dy, xi = x0 + dx;
            const bool ok = (yi >= 0) && (yi < 64) && (xi >= 0) && (xi < 64) && !inval;
            const float w = (dy ? wy : 1.f - wy) * (dx ? wx : 1.f - wx);
            const u32 idx = ok ? (u32)(yi * 64 + xi) : 0u;
            const u16 hw = ok ? __half_as_ushort(__float2half_rn(w)) : (u16)0;
            taps[t][tt] = (idx << 16) | hw;
        }
    }
    const bool vld = valid[s] != 0;
    __syncthreads();

    const int rp = t >> 2;            // 0..63
    const int c8 = (t & 3) << 3;      // 0,8,16,24
    const u16* kvbase = KV + (size_t)b * 4096 * 512 + h * 32;

    auto samp = [&](int voff) {       // voff: 0 for K, 256 for V
        const u16* baseI = kvbase + voff;
        float ck[8];
#pragma unroll
        for (int jx = 0; jx < 8; ++jx) ck[jx] = ckv[voff + h * 32 + c8 + jx];
        for (int p0 = 0; p0 < 225; p0 += 64) {
            const int p = p0 + rp;
            if (p < 225) {
                float a[8];
#pragma unroll
                for (int jx = 0; jx < 8; ++jx) a[jx] = ck[jx];
#pragma unroll
                for (int tt = 0; tt < 4; ++tt) {
                    const u32 u = taps[p][tt];
                    const float w = __half2float(__ushort_as_half((u16)(u & 0xffffu)));
                    const u16x8 v = *(const u16x8*)(baseI + (size_t)(u >> 16) * 512 + c8);
#pragma unroll
                    for (int jx = 0; jx < 8; ++jx) a[jx] += w * b2f(v[jx]);
                }
                u16x8 o;
#pragma unroll
                for (int jx = 0; jx < 8; ++jx) o[jx] = f2b(a[jx]);
                *(u16x8*)(&kv_s[p][c8]) = o;
            }
        }
    };

    // ---- K ----
    samp(0);
    __syncthreads();

    // ---- scores ----
    for (int j = jj; j < 225; j += 16) {
        float acc = 0.0f;
#pragma unroll
        for (int d = 0; d < 32; d += 2) {
            const u32 u = *(const u32*)(&kv_s[j][d]);
            acc += q_s[i][d] * b2f((u16)u) + q_s[i][d + 1] * b2f((u16)(u >> 16));
        }
        float sv = acc * 0.17677669529663687f;
        if (!vld && j > 0) sv = -1e30f;
        s_s[i][j] = sv;
    }
    __syncthreads();

    // ---- softmax over 225 per row ----
    float pm = -1e30f;
    for (int j = jj; j < 225; j += 16) pm = fmaxf(pm, s_s[i][j]);
    red[i][jj] = pm;
    __syncthreads();
    if (t < 16) {
        float m = red[t][0];
#pragma unroll
        for (int x = 1; x < 16; ++x) m = fmaxf(m, red[t][x]);
        rowm[t] = m;
    }
    __syncthreads();
    const float mx = rowm[i];
    float ps = 0.0f;
    for (int j = jj; j < 225; j += 16) {
        const float e = __expf(s_s[i][j] - mx);
        s_s[i][j] = e;
        ps += e;
    }
    red[i][jj] = ps;
    __syncthreads();
    if (t < 16) {
        float sm = 0.0f;
#pragma unroll
        for (int x = 0; x < 16; ++x) sm += red[t][x];
        rowsum[t] = sm;
    }
    __syncthreads();

    // ---- V (overwrite kv_s) ----
    samp(256);
    __syncthreads();

    // ---- PV ----
    const int d0 = jj * 2;
    float o0 = 0.0f, o1 = 0.0f;
    for (int j = 0; j < 225; ++j) {
        const float p = s_s[i][j];
        const u32 u = *(const u32*)(&kv_s[j][d0]);
        o0 = fmaf(p, b2f((u16)u), o0);
        o1 = fmaf(p, b2f((u16)(u >> 16)), o1);
    }
    const float inv = 1.0f / rowsum[i];
    const u32 ob = (u32)f2b(o0 * inv) | ((u32)f2b(o1 * inv) << 16);
    *(u32*)(O + (size_t)(s * 16 + i) * 256 + h * 32 + d0) = ob;
}

// ---------- residual add + LayerNorm; writes fp32 X and bf16 Xb ------------
__global__ LB void k_add_ln(float* __restrict__ X, u16* __restrict__ Xb,
                            const float* __restrict__ D,
                            const float* __restrict__ w, const float* __restrict__ b)
{
    const int row  = blockIdx.x * 4 + (threadIdx.x >> 6);
    const int lane = threadIdx.x & 63;
    float4 x = ((const float4*)(X + (size_t)row * 256))[lane];
    const float4 d = ((const float4*)(D + (size_t)row * 256))[lane];
    x.x += d.x; x.y += d.y; x.z += d.z; x.w += d.w;
    float s = x.x + x.y + x.z + x.w;
#pragma unroll
    for (int m = 1; m < 64; m <<= 1) s += __shfl_xor(s, m);
    const float mu = s * (1.0f / 256.0f);
    const float4 c = make_float4(x.x - mu, x.y - mu, x.z - mu, x.w - mu);
    float q = c.x * c.x + c.y * c.y + c.z * c.z + c.w * c.w;
#pragma unroll
    for (int m = 1; m < 64; m <<= 1) q += __shfl_xor(q, m);
    const float inv = 1.0f / sqrtf(q * (1.0f / 256.0f) + 1e-5f);
    const float4 w4 = ((const float4*)w)[lane];
    const float4 b4 = ((const float4*)b)[lane];
    float4 o;
    o.x = c.x * inv * w4.x + b4.x;
    o.y = c.y * inv * w4.y + b4.y;
    o.z = c.z * inv * w4.z + b4.z;
    o.w = c.w * inv * w4.w + b4.w;
    ((float4*)(X + (size_t)row * 256))[lane] = o;
    ushort4 ob;
    ob.x = f2b(o.x); ob.y = f2b(o.y); ob.z = f2b(o.z); ob.w = f2b(o.w);
    ((ushort4*)(Xb + (size_t)row * 256))[lane] = ob;
}

// ---------- output head: (8192,256) @ (4,256)^T + b ------------------------
__global__ LB void k_out(const float* __restrict__ X, const float* __restrict__ W,
                         const float* __restrict__ bias, float* __restrict__ O)
{
    __shared__ float w_s[4][260];
    const int t = threadIdx.x;
    for (int e = t; e < 1024; e += 256) w_s[e >> 8][e & 255] = W[e];
    __syncthreads();
    const int row = blockIdx.x * 64 + (t >> 2);
    const int j = t & 3;
    const float4* xr = (const float4*)(X + (size_t)row * 256);
    float acc = 0.0f;
#pragma unroll
    for (int k4 = 0; k4 < 64; ++k4) {
        const float4 x = xr[k4];
        acc += x.x * w_s[j][k4 * 4]     + x.y * w_s[j][k4 * 4 + 1]
             + x.z * w_s[j][k4 * 4 + 2] + x.w * w_s[j][k4 * 4 + 3];
    }
    O[(size_t)row * 4 + j] = acc + bias[j];
}

// ---------------------------------------------------------------------------
extern "C" void kernel_launch(void* const* d_in, const int* in_sizes, int n_in,
                              void* d_out, int out_size, void* d_ws, size_t ws_size,
                              hipStream_t stream)
{
    const float* img          = (const float*)d_in[0];
    const float* kps          = (const float*)d_in[1];
    const unsigned char* vmsk = (const unsigned char*)d_in[2];
    const float* proj_w       = (const float*)d_in[3];
    const float* proj_b       = (const float*)d_in[4];
    const float* query_embed  = (const float*)d_in[5];
    const float* self_qkv_w   = (const float*)d_in[6];
    const float* self_qkv_b   = (const float*)d_in[7];
    const float* self_out_w   = (const float*)d_in[8];
    const float* self_out_b   = (const float*)d_in[9];
    const float* cross_qkv_w  = (const float*)d_in[10];
    const float* cross_qkv_b  = (const float*)d_in[11];
    const float* cross_out_w  = (const float*)d_in[12];
    const float* cross_out_b  = (const float*)d_in[13];
    const float* ffn1_w       = (const float*)d_in[14];
    const float* ffn1_b       = (const float*)d_in[15];
    const float* ffn2_w       = (const float*)d_in[16];
    const float* ffn2_b       = (const float*)d_in[17];
    const float* ln1_w        = (const float*)d_in[18];
    const float* ln1_b        = (const float*)d_in[19];
    const float* ln2_w        = (const float*)d_in[20];
    const float* ln2_b        = (const float*)d_in[21];
    const float* ln3_w        = (const float*)d_in[22];
    const float* ln3_b        = (const float*)d_in[23];
    const float* out_w        = (const float*)d_in[24];
    const float* out_b        = (const float*)d_in[25];
    float* out = (float*)d_out;

    // ---- workspace layout ----
    char* W8 = (char*)d_ws;
    size_t off = 0;
    auto alloc = [&](size_t bytes) { void* p = W8 + off; off += (bytes + 255) & ~(size_t)255; return p; };
    float* tgt   = (float*)alloc(2097152 * 4);
    float* Qbuf  = (float*)alloc(2097152 * 4);
    float* Pbuf  = (float*)alloc(2097152 * 4);
    float* Sbuf  = (float*)alloc(6291456 * 4);
    float* ckv   = (float*)alloc(512 * 4);
    u16* imgTb   = (u16*)alloc(2097152 * 2);
    u16* imgPb   = (u16*)alloc(2097152 * 2);
    u16* KVb     = (u16*)alloc(4194304 * 2);
    u16* tgtb    = (u16*)alloc(2097152 * 2);
    u16* Abuf    = (u16*)alloc(2097152 * 2);
    u16* Hbuf    = (u16*)alloc(8388608 * 2);
    u16* wAll    = (u16*)alloc(3211264 * 2);
    int* valid   = (int*)alloc(512 * 4);

    u16* wProj = wAll;             // 65536
    u16* wSQKV = wProj + 65536;    // 3*768*256
    u16* wSOut = wSQKV + 589824;   // 3*256*256
    u16* wCQKV = wSOut + 196608;   // 3*768*256
    u16* wCOut = wCQKV + 589824;   // 3*256*256
    u16* wF1   = wCOut + 196608;   // 3*1024*256
    u16* wF2   = wF1 + 786432;     // 3*256*1024

    k_mask<<<1, 256, 0, stream>>>(vmsk, valid);
    k_wconv<<<12544, 256, 0, stream>>>(proj_w, self_qkv_w, self_out_w, cross_qkv_w,
                                       cross_out_w, ffn1_w, ffn2_w, wAll);
    k_transpose<<<dim3(64, 4, 2), 256, 0, stream>>>(img, imgTb);
    // imgP = imgT @ proj_w^T (bias folded into ckv)
    gemm_mfma<64><<<dim3(2, 128), 256, 0, stream>>>(imgTb, wProj, nullptr,
                                                    nullptr, imgPb, 8192, 256, 256, 0);
    k_init_tgt<<<8192, 256, 0, stream>>>(tgt, tgtb, query_embed);

    for (int l = 0; l < 3; ++l) {
        // ---- self attention ----
        gemm_mfma<128><<<dim3(6, 64), 256, 0, stream>>>(tgtb, wSQKV + (size_t)l * 196608,
            self_qkv_b + (size_t)l * 768, Sbuf, nullptr, 8192, 768, 256, 0);
        k_self_attn<<<4096, 256, 0, stream>>>(Sbuf, Abuf);
        gemm_mfma<64><<<dim3(2, 128), 256, 0, stream>>>(Abuf, wSOut + (size_t)l * 65536,
            self_out_b + (size_t)l * 256, Pbuf, nullptr, 8192, 256, 256, 0);
        k_add_ln<<<2048, 256, 0, stream>>>(tgt, tgtb, Pbuf,
            ln1_w + (size_t)l * 256, ln1_b + (size_t)l * 256);

        // ---- cross attention ----
        gemm_mfma<64><<<dim3(2, 128), 256, 0, stream>>>(tgtb, wCQKV + (size_t)l * 196608,
            cross_qkv_b + (size_t)l * 768, Qbuf, nullptr, 8192, 256, 256, 0);
        gemm_mfma<128><<<dim3(4, 64), 256, 0, stream>>>(imgPb,
            wCQKV + (size_t)l * 196608 + 65536, nullptr,
            nullptr, KVb, 8192, 512, 256, 0);
        k_bias_combo<<<1, 256, 0, stream>>>(proj_b,
            cross_qkv_w + (size_t)l * 196608 + 65536, cross_qkv_b + (size_t)l * 768 + 256,
            cross_qkv_w + (size_t)l * 196608 + 131072, cross_qkv_b + (size_t)l * 768 + 512,
            ckv);
        k_cross_attn<<<4096, 256, 0, stream>>>(Qbuf, KVb, ckv, valid, kps, Abuf);
        gemm_mfma<64><<<dim3(2, 128), 256, 0, stream>>>(Abuf, wCOut + (size_t)l * 65536,
            cross_out_b + (size_t)l * 256, Pbuf, nullptr, 8192, 256, 256, 0);
        k_add_ln<<<2048, 256, 0, stream>>>(tgt, tgtb, Pbuf,
            ln2_w + (size_t)l * 256, ln2_b + (size_t)l * 256);

        // ---- FFN ----
        gemm_mfma<128><<<dim3(8, 64), 256, 0, stream>>>(tgtb, wF1 + (size_t)l * 262144,
            ffn1_b + (size_t)l * 1024, nullptr, Hbuf, 8192, 1024, 256, 1);
        gemm_mfma<64><<<dim3(2, 128), 256, 0, stream>>>(Hbuf, wF2 + (size_t)l * 262144,
            ffn2_b + (size_t)l * 256, Pbuf, nullptr, 8192, 256, 1024, 0);
        k_add_ln<<<2048, 256, 0, stream>>>(tgt, tgtb, Pbuf,
            ln3_w + (size_t)l * 256, ln3_b + (size_t)l * 256);
    }

    k_out<<<128, 256, 0, stream>>>(tgt, out_w, out_b, out);
}

// Round 7
// 603.688 us; speedup vs baseline: 2.3219x; 1.0584x over previous
//
#include <hip/hip_runtime.h>
#include <hip/hip_fp16.h>

#define LB __launch_bounds__(256)

typedef unsigned short u16;
typedef unsigned int   u32;
typedef __attribute__((ext_vector_type(8))) short bf16x8;   // 8 bf16 (4 VGPRs)
typedef __attribute__((ext_vector_type(4))) float f32x4;
typedef __attribute__((ext_vector_type(8))) u16  u16x8;

__device__ __forceinline__ u16 f2b(float f) {
    u32 u = __float_as_uint(f);
    u32 r = (u + 0x7fffu + ((u >> 16) & 1u)) >> 16;
    return (u16)r;
}
__device__ __forceinline__ float b2f(u16 h) {
    return __uint_as_float((u32)h << 16);
}

// ---------------------------------------------------------------------------
// B=2 N=256 C=256 HF=WF=64 ROI=15(225) HID=256 HEADS=8 Dh=32 DEPTH=3 FFN=1024
// NQ=16 -> seqs S=512, MT=8192. Linearity: K = sample(imgP@Wk^T) + ckv.
// Round-4-verified cross-attn path kept bit-exact; prep work fused into one
// k_prep dispatch (mask detect + all 3 layers' ck/cv constants).
// ---------------------------------------------------------------------------

// ---------- fused prep: mask dtype detect + per-layer ck/cv ----------------
__global__ void k_prep(const unsigned char* __restrict__ m, int* __restrict__ valid,
                       const float* __restrict__ pb,
                       const float* __restrict__ cqkv_w,
                       const float* __restrict__ cqkv_b,
                       float* __restrict__ ckv)
{
    if (blockIdx.x == 0) {
        __shared__ int flag;
        if (threadIdx.x == 0) flag = 0;
        __syncthreads();
        int loc = 0;
        for (int off = threadIdx.x; off < 512; off += 256)
            if ((off & 3) != 0 && m[off] != 0) loc = 1;
        if (loc) atomicOr(&flag, 1);
        __syncthreads();
        const bool bytelay = (flag != 0);
        for (int s = threadIdx.x; s < 512; s += 256)
            valid[s] = bytelay ? (int)(m[s] != 0) : (int)(((const int*)m)[s] != 0);
    } else {
        const int l = blockIdx.x - 1;   // 0..2
        const float* Wk = cqkv_w + (size_t)l * 196608 + 65536;
        const float* Wv = cqkv_w + (size_t)l * 196608 + 131072;
        const float* kb = cqkv_b + (size_t)l * 768 + 256;
        const float* vb = cqkv_b + (size_t)l * 768 + 512;
        const int o = threadIdx.x;
        float a = 0.f, c = 0.f;
        for (int cc = 0; cc < 256; cc += 4) {
            const float4 p4 = *(const float4*)(pb + cc);
            const float4 k4 = *(const float4*)(Wk + (size_t)o * 256 + cc);
            const float4 v4 = *(const float4*)(Wv + (size_t)o * 256 + cc);
            a += p4.x * k4.x + p4.y * k4.y + p4.z * k4.z + p4.w * k4.w;
            c += p4.x * v4.x + p4.y * v4.y + p4.z * v4.z + p4.w * v4.w;
        }
        ckv[l * 512 + o]       = a + kb[o];
        ckv[l * 512 + 256 + o] = c + vb[o];
    }
}

// ---------- weights fp32 -> bf16 arena -------------------------------------
__global__ LB void k_wconv(const float* __restrict__ s0, const float* __restrict__ s1,
                           const float* __restrict__ s2, const float* __restrict__ s3,
                           const float* __restrict__ s4, const float* __restrict__ s5,
                           const float* __restrict__ s6, u16* __restrict__ dst)
{
    const int e = blockIdx.x * 256 + threadIdx.x;
    if (e >= 3211264) return;
    float v;
    int i = e;
    if (i < 65536) v = s0[i];
    else if ((i -= 65536) < 589824) v = s1[i];
    else if ((i -= 589824) < 196608) v = s2[i];
    else if ((i -= 196608) < 589824) v = s3[i];
    else if ((i -= 589824) < 196608) v = s4[i];
    else if ((i -= 196608) < 786432) v = s5[i];
    else { i -= 786432; v = s6[i]; }
    dst[e] = f2b(v);
}

// ---------- transpose image (B,C,64,64) -> (B,4096,C) bf16 -----------------
__global__ LB void k_transpose(const float* __restrict__ img, u16* __restrict__ imgTb)
{
    __shared__ float tile[64][65];
    const int b  = blockIdx.z;
    const int c0 = blockIdx.y * 64;
    const int p0 = blockIdx.x * 64;
    const int t  = threadIdx.x;
    const int tr = t >> 6, tc = t & 63;
#pragma unroll
    for (int p = 0; p < 16; ++p) {
        const int i = p * 4 + tr;
        tile[i][tc] = img[((size_t)(b * 256 + c0 + i)) * 4096 + p0 + tc];
    }
    __syncthreads();
#pragma unroll
    for (int p = 0; p < 16; ++p) {
        const int jj = p * 4 + tr;
        imgTb[((size_t)(b * 4096 + p0 + jj)) * 256 + c0 + tc] = f2b(tile[tc][jj]);
    }
}

// ---------- bf16 MFMA GEMM: C[M,N] = A[M,K](bf16) @ W[N,K](bf16)^T + bias --
// BM in {64,128}, BN=128, BK=64, 4 waves (2x2), 16x16x32 MFMA.
// LDS rows are 128B; XOR swizzle slot^=(row&7) on BOTH global-src and ds_read.
template<int BM>
__global__ LB void gemm_mfma(const u16* __restrict__ A, const u16* __restrict__ W,
                             const float* __restrict__ bias,
                             float* __restrict__ Cf, u16* __restrict__ Cb,
                             int M, int N, int K, int relu)
{
    constexpr int BN = 128;
    __shared__ u16 lds[2][(BM + BN) * 64];
    const int t = threadIdx.x;
    const int wid = t >> 6, lane = t & 63;
    const int bm = blockIdx.y * BM, bn = blockIdx.x * BN;
    const int KT = K >> 6;

    auto stage = [&](int buf, int kt) {
        const int k0 = kt * 64;
        const int rr = t >> 3;
        const int u  = t & 7;
#pragma unroll
        for (int q = 0; q < BM / 32; ++q) {
            const int r = q * 32 + rr;
            const u16* src = A + (size_t)(bm + r) * K + k0 + ((u ^ (r & 7)) << 3);
            __builtin_amdgcn_global_load_lds(
                (const __attribute__((address_space(1))) void*)src,
                (__attribute__((address_space(3))) void*)&lds[buf][q * 2048 + wid * 512],
                16, 0, 0);
        }
#pragma unroll
        for (int q = 0; q < 4; ++q) {
            const int r = q * 32 + rr;
            const u16* src = W + (size_t)(bn + r) * K + k0 + ((u ^ (r & 7)) << 3);
            __builtin_amdgcn_global_load_lds(
                (const __attribute__((address_space(1))) void*)src,
                (__attribute__((address_space(3))) void*)&lds[buf][BM * 64 + q * 2048 + wid * 512],
                16, 0, 0);
        }
    };

    const int wr = wid >> 1, wc = wid & 1;
    constexpr int MR = BM / 32;
    f32x4 acc[MR][4];
    const f32x4 z = {0.f, 0.f, 0.f, 0.f};
#pragma unroll
    for (int mi = 0; mi < MR; ++mi)
#pragma unroll
        for (int ni = 0; ni < 4; ++ni) acc[mi][ni] = z;

    const int r16 = lane & 15, kg = lane >> 4;

    stage(0, 0);
    int cur = 0;
    for (int kt = 0; kt < KT; ++kt) {
        asm volatile("s_waitcnt vmcnt(0)" ::: "memory");
        __syncthreads();
        if (kt + 1 < KT) stage(cur ^ 1, kt + 1);
        const u16* pA = lds[cur];
        const u16* pB = lds[cur] + BM * 64;
#pragma unroll
        for (int kk = 0; kk < 2; ++kk) {
            const int s = kk * 4 + kg;
            bf16x8 afr[MR], bfr[4];
#pragma unroll
            for (int mi = 0; mi < MR; ++mi) {
                const int r = wr * (BM / 2) + mi * 16 + r16;
                afr[mi] = *(const bf16x8*)(pA + r * 64 + ((s ^ (r & 7)) << 3));
            }
#pragma unroll
            for (int ni = 0; ni < 4; ++ni) {
                const int c = wc * 64 + ni * 16 + r16;
                bfr[ni] = *(const bf16x8*)(pB + c * 64 + ((s ^ (c & 7)) << 3));
            }
#pragma unroll
            for (int mi = 0; mi < MR; ++mi)
#pragma unroll
                for (int ni = 0; ni < 4; ++ni)
                    acc[mi][ni] = __builtin_amdgcn_mfma_f32_16x16x32_bf16(
                        afr[mi], bfr[ni], acc[mi][ni], 0, 0, 0);
        }
        cur ^= 1;
    }

#pragma unroll
    for (int mi = 0; mi < MR; ++mi) {
#pragma unroll
        for (int ni = 0; ni < 4; ++ni) {
            const int col = bn + wc * 64 + ni * 16 + r16;
            const float bs = bias ? bias[col] : 0.0f;
#pragma unroll
            for (int rg = 0; rg < 4; ++rg) {
                const int row = bm + wr * (BM / 2) + mi * 16 + kg * 4 + rg;
                float v = acc[mi][ni][rg] + bs;
                if (relu) v = fmaxf(v, 0.0f);
                if (Cf) Cf[(size_t)row * N + col] = v;
                if (Cb) Cb[(size_t)row * N + col] = f2b(v);
            }
        }
    }
}

// ---------- init tgt (fp32 + bf16) -----------------------------------------
__global__ LB void k_init_tgt(float* __restrict__ tgt, u16* __restrict__ tgtb,
                              const float* __restrict__ qe)
{
    const int e = blockIdx.x * 256 + threadIdx.x;
    const int c = e & 255;
    const int row = e >> 8;
    const int i = row & 15;
    const float v = qe[(i << 8) | c];
    tgt[e] = v;
    tgtb[e] = f2b(v);
}

// ---------- self attention: per (seq, head), 16q x 16k, Dh=32; out bf16 ----
__global__ LB void k_self_attn(const float* __restrict__ QKV, u16* __restrict__ O)
{
    const int blk = blockIdx.x;
    const int s = blk >> 3, h = blk & 7;
    __shared__ float q_s[16][36], k_s[16][36], v_s[16][36];
    __shared__ float e_s[16][17];
    __shared__ float rsum[16];
    const int t = threadIdx.x;
    const int i = t >> 4, j = t & 15;

    const float* basep = QKV + (size_t)(s * 16 + i) * 768 + h * 32;
    q_s[i][j]      = basep[j];
    q_s[i][j + 16] = basep[j + 16];
    k_s[i][j]      = basep[256 + j];
    k_s[i][j + 16] = basep[256 + j + 16];
    v_s[i][j]      = basep[512 + j];
    v_s[i][j + 16] = basep[512 + j + 16];
    __syncthreads();

    float acc = 0.0f;
#pragma unroll
    for (int d = 0; d < 32; d += 4) {
        const float4 q4 = *(const float4*)(&q_s[i][d]);
        const float4 k4 = *(const float4*)(&k_s[j][d]);
        acc += q4.x * k4.x + q4.y * k4.y + q4.z * k4.z + q4.w * k4.w;
    }
    const float sc = acc * 0.17677669529663687f;
    e_s[i][j] = sc;
    __syncthreads();
    float mx = e_s[i][0];
#pragma unroll
    for (int x = 1; x < 16; ++x) mx = fmaxf(mx, e_s[i][x]);
    const float e = __expf(sc - mx);
    __syncthreads();
    e_s[i][j] = e;
    __syncthreads();
    if (j == 0) {
        float sm = 0.0f;
#pragma unroll
        for (int x = 0; x < 16; ++x) sm += e_s[i][x];
        rsum[i] = sm;
    }
    __syncthreads();

    const int oi = t >> 5;
    const int d  = t & 31;
#pragma unroll
    for (int pass = 0; pass < 2; ++pass) {
        const int r = oi + pass * 8;
        float o = 0.0f;
#pragma unroll
        for (int x = 0; x < 16; ++x) o += e_s[r][x] * v_s[x][d];
        O[(size_t)(s * 16 + r) * 256 + h * 32 + d] = f2b(o / rsum[r]);
    }
}

// ---------- fused cross attention with on-the-fly ROI sampling (bf16 KV) ---
// Round-4-verified path, bit-exact. ckv points at this layer's [512] block.
__global__ LB void k_cross_attn(const float* __restrict__ Q,
                                const u16* __restrict__ KV,   // [B*4096][512] bf16
                                const float* __restrict__ ckv,
                                const int* __restrict__ valid,
                                const float* __restrict__ kps,
                                u16* __restrict__ O)
{
    const int blk = blockIdx.x;
    const int s = blk >> 3, h = blk & 7;
    const int b = s >> 8, n = s & 255;
    __shared__ u32   taps[225][4];       // idx<<16 | fp16 weight
    __shared__ u16   kv_s[225][40];      // bf16
    __shared__ float q_s[16][36];
    __shared__ float s_s[16][225];
    __shared__ float red[16][17];
    __shared__ float rowm[16], rowsum[16];
    const int t = threadIdx.x;
    const int i = t >> 4, jj = t & 15;

    q_s[i][jj]      = Q[(size_t)(s * 16 + i) * 256 + h * 32 + jj];
    q_s[i][jj + 16] = Q[(size_t)(s * 16 + i) * 256 + h * 32 + jj + 16];

    if (t < 225) {
        const float kpy = kps[(b * 256 + n) * 2 + 0];
        const float kpx = kps[(b * 256 + n) * 2 + 1];
        const int iy = t / 15, ix = t - iy * 15;
        const float gy = rintf(kpy) + (float)(iy - 7);
        const float gx = rintf(kpx) + (float)(ix - 7);
        const float gxn = gx / 511.0f * 2.0f - 1.0f;
        const float gyn = gy / 511.0f * 2.0f - 1.0f;
        const bool inval = (gxn < -1.f) || (gyn < -1.f) || (gxn > 1.f) || (gyn > 1.f);
        const float x = ((gxn + 1.f) * 64.f - 1.f) * 0.5f;
        const float y = ((gyn + 1.f) * 64.f - 1.f) * 0.5f;
        const float x0f = floorf(x), y0f = floorf(y);
        const float wx = x - x0f, wy = y - y0f;
        const int x0 = (int)x0f, y0 = (int)y0f;
#pragma unroll
        for (int tt = 0; tt < 4; ++tt) {
            const int dy = tt >> 1, dx = tt & 1;
            const int yi = y0 + dy, xi = x0 + dx;
            const bool ok = (yi >= 0) && (yi < 64) && (xi >= 0) && (xi < 64) && !inval;
            const float w = (dy ? wy : 1.f - wy) * (dx ? wx : 1.f - wx);
            const u32 idx = ok ? (u32)(yi * 64 + xi) : 0u;
            const u16 hw = ok ? __half_as_ushort(__float2half_rn(w)) : (u16)0;
            taps[t][tt] = (idx << 16) | hw;
        }
    }
    const bool vld = valid[s] != 0;
    __syncthreads();

    const int rp = t >> 2;            // 0..63
    const int c8 = (t & 3) << 3;      // 0,8,16,24
    const u16* kvbase = KV + (size_t)b * 4096 * 512 + h * 32;

    auto samp = [&](int voff) {       // voff: 0 for K, 256 for V
        const u16* baseI = kvbase + voff;
        float ck[8];
#pragma unroll
        for (int jx = 0; jx < 8; ++jx) ck[jx] = ckv[voff + h * 32 + c8 + jx];
        for (int p0 = 0; p0 < 225; p0 += 64) {
            const int p = p0 + rp;
            if (p < 225) {
                float a[8];
#pragma unroll
                for (int jx = 0; jx < 8; ++jx) a[jx] = ck[jx];
#pragma unroll
                for (int tt = 0; tt < 4; ++tt) {
                    const u32 u = taps[p][tt];
                    const float w = __half2float(__ushort_as_half((u16)(u & 0xffffu)));
                    const u16x8 v = *(const u16x8*)(baseI + (size_t)(u >> 16) * 512 + c8);
#pragma unroll
                    for (int jx = 0; jx < 8; ++jx) a[jx] += w * b2f(v[jx]);
                }
                u16x8 o;
#pragma unroll
                for (int jx = 0; jx < 8; ++jx) o[jx] = f2b(a[jx]);
                *(u16x8*)(&kv_s[p][c8]) = o;
            }
        }
    };

    // ---- K ----
    samp(0);
    __syncthreads();

    // ---- scores ----
    for (int j = jj; j < 225; j += 16) {
        float acc = 0.0f;
#pragma unroll
        for (int d = 0; d < 32; d += 2) {
            const u32 u = *(const u32*)(&kv_s[j][d]);
            acc += q_s[i][d] * b2f((u16)u) + q_s[i][d + 1] * b2f((u16)(u >> 16));
        }
        float sv = acc * 0.17677669529663687f;
        if (!vld && j > 0) sv = -1e30f;
        s_s[i][j] = sv;
    }
    __syncthreads();

    // ---- softmax over 225 per row ----
    float pm = -1e30f;
    for (int j = jj; j < 225; j += 16) pm = fmaxf(pm, s_s[i][j]);
    red[i][jj] = pm;
    __syncthreads();
    if (t < 16) {
        float m = red[t][0];
#pragma unroll
        for (int x = 1; x < 16; ++x) m = fmaxf(m, red[t][x]);
        rowm[t] = m;
    }
    __syncthreads();
    const float mx = rowm[i];
    float ps = 0.0f;
    for (int j = jj; j < 225; j += 16) {
        const float e = __expf(s_s[i][j] - mx);
        s_s[i][j] = e;
        ps += e;
    }
    red[i][jj] = ps;
    __syncthreads();
    if (t < 16) {
        float sm = 0.0f;
#pragma unroll
        for (int x = 0; x < 16; ++x) sm += red[t][x];
        rowsum[t] = sm;
    }
    __syncthreads();

    // ---- V (overwrite kv_s) ----
    samp(256);
    __syncthreads();

    // ---- PV ----
    const int d0 = jj * 2;
    float o0 = 0.0f, o1 = 0.0f;
    for (int j = 0; j < 225; ++j) {
        const float p = s_s[i][j];
        const u32 u = *(const u32*)(&kv_s[j][d0]);
        o0 = fmaf(p, b2f((u16)u), o0);
        o1 = fmaf(p, b2f((u16)(u >> 16)), o1);
    }
    const float inv = 1.0f / rowsum[i];
    const u32 ob = (u32)f2b(o0 * inv) | ((u32)f2b(o1 * inv) << 16);
    *(u32*)(O + (size_t)(s * 16 + i) * 256 + h * 32 + d0) = ob;
}

// ---------- residual add + LayerNorm; writes fp32 X and bf16 Xb ------------
__global__ LB void k_add_ln(float* __restrict__ X, u16* __restrict__ Xb,
                            const float* __restrict__ D,
                            const float* __restrict__ w, const float* __restrict__ b)
{
    const int row  = blockIdx.x * 4 + (threadIdx.x >> 6);
    const int lane = threadIdx.x & 63;
    float4 x = ((const float4*)(X + (size_t)row * 256))[lane];
    const float4 d = ((const float4*)(D + (size_t)row * 256))[lane];
    x.x += d.x; x.y += d.y; x.z += d.z; x.w += d.w;
    float s = x.x + x.y + x.z + x.w;
#pragma unroll
    for (int m = 1; m < 64; m <<= 1) s += __shfl_xor(s, m);
    const float mu = s * (1.0f / 256.0f);
    const float4 c = make_float4(x.x - mu, x.y - mu, x.z - mu, x.w - mu);
    float q = c.x * c.x + c.y * c.y + c.z * c.z + c.w * c.w;
#pragma unroll
    for (int m = 1; m < 64; m <<= 1) q += __shfl_xor(q, m);
    const float inv = 1.0f / sqrtf(q * (1.0f / 256.0f) + 1e-5f);
    const float4 w4 = ((const float4*)w)[lane];
    const float4 b4 = ((const float4*)b)[lane];
    float4 o;
    o.x = c.x * inv * w4.x + b4.x;
    o.y = c.y * inv * w4.y + b4.y;
    o.z = c.z * inv * w4.z + b4.z;
    o.w = c.w * inv * w4.w + b4.w;
    ((float4*)(X + (size_t)row * 256))[lane] = o;
    ushort4 ob;
    ob.x = f2b(o.x); ob.y = f2b(o.y); ob.z = f2b(o.z); ob.w = f2b(o.w);
    ((ushort4*)(Xb + (size_t)row * 256))[lane] = ob;
}

// ---------- output head: (8192,256) @ (4,256)^T + b ------------------------
__global__ LB void k_out(const float* __restrict__ X, const float* __restrict__ W,
                         const float* __restrict__ bias, float* __restrict__ O)
{
    __shared__ float w_s[4][260];
    const int t = threadIdx.x;
    for (int e = t; e < 1024; e += 256) w_s[e >> 8][e & 255] = W[e];
    __syncthreads();
    const int row = blockIdx.x * 64 + (t >> 2);
    const int j = t & 3;
    const float4* xr = (const float4*)(X + (size_t)row * 256);
    float acc = 0.0f;
#pragma unroll
    for (int k4 = 0; k4 < 64; ++k4) {
        const float4 x = xr[k4];
        acc += x.x * w_s[j][k4 * 4]     + x.y * w_s[j][k4 * 4 + 1]
             + x.z * w_s[j][k4 * 4 + 2] + x.w * w_s[j][k4 * 4 + 3];
    }
    O[(size_t)row * 4 + j] = acc + bias[j];
}

// ---------------------------------------------------------------------------
extern "C" void kernel_launch(void* const* d_in, const int* in_sizes, int n_in,
                              void* d_out, int out_size, void* d_ws, size_t ws_size,
                              hipStream_t stream)
{
    const float* img          = (const float*)d_in[0];
    const float* kps          = (const float*)d_in[1];
    const unsigned char* vmsk = (const unsigned char*)d_in[2];
    const float* proj_w       = (const float*)d_in[3];
    const float* proj_b       = (const float*)d_in[4];
    const float* query_embed  = (const float*)d_in[5];
    const float* self_qkv_w   = (const float*)d_in[6];
    const float* self_qkv_b   = (const float*)d_in[7];
    const float* self_out_w   = (const float*)d_in[8];
    const float* self_out_b   = (const float*)d_in[9];
    const float* cross_qkv_w  = (const float*)d_in[10];
    const float* cross_qkv_b  = (const float*)d_in[11];
    const float* cross_out_w  = (const float*)d_in[12];
    const float* cross_out_b  = (const float*)d_in[13];
    const float* ffn1_w       = (const float*)d_in[14];
    const float* ffn1_b       = (const float*)d_in[15];
    const float* ffn2_w       = (const float*)d_in[16];
    const float* ffn2_b       = (const float*)d_in[17];
    const float* ln1_w        = (const float*)d_in[18];
    const float* ln1_b        = (const float*)d_in[19];
    const float* ln2_w        = (const float*)d_in[20];
    const float* ln2_b        = (const float*)d_in[21];
    const float* ln3_w        = (const float*)d_in[22];
    const float* ln3_b        = (const float*)d_in[23];
    const float* out_w        = (const float*)d_in[24];
    const float* out_b        = (const float*)d_in[25];
    float* out = (float*)d_out;

    // ---- workspace layout ----
    char* W8 = (char*)d_ws;
    size_t off = 0;
    auto alloc = [&](size_t bytes) { void* p = W8 + off; off += (bytes + 255) & ~(size_t)255; return p; };
    float* tgt   = (float*)alloc(2097152 * 4);
    float* Qbuf  = (float*)alloc(2097152 * 4);
    float* Pbuf  = (float*)alloc(2097152 * 4);
    float* Sbuf  = (float*)alloc(6291456 * 4);
    float* ckv   = (float*)alloc(3 * 512 * 4);
    u16* imgTb   = (u16*)alloc(2097152 * 2);
    u16* imgPb   = (u16*)alloc(2097152 * 2);
    u16* KVb     = (u16*)alloc(4194304 * 2);
    u16* tgtb    = (u16*)alloc(2097152 * 2);
    u16* Abuf    = (u16*)alloc(2097152 * 2);
    u16* Hbuf    = (u16*)alloc(8388608 * 2);
    u16* wAll    = (u16*)alloc(3211264 * 2);
    int* valid   = (int*)alloc(512 * 4);

    u16* wProj = wAll;             // 65536
    u16* wSQKV = wProj + 65536;    // 3*768*256
    u16* wSOut = wSQKV + 589824;   // 3*256*256
    u16* wCQKV = wSOut + 196608;   // 3*768*256
    u16* wCOut = wCQKV + 589824;   // 3*256*256
    u16* wF1   = wCOut + 196608;   // 3*1024*256
    u16* wF2   = wF1 + 786432;     // 3*256*1024

    k_prep<<<4, 256, 0, stream>>>(vmsk, valid, proj_b, cross_qkv_w, cross_qkv_b, ckv);
    k_wconv<<<12544, 256, 0, stream>>>(proj_w, self_qkv_w, self_out_w, cross_qkv_w,
                                       cross_out_w, ffn1_w, ffn2_w, wAll);
    k_transpose<<<dim3(64, 4, 2), 256, 0, stream>>>(img, imgTb);
    // imgP = imgT @ proj_w^T (bias folded into ckv)
    gemm_mfma<64><<<dim3(2, 128), 256, 0, stream>>>(imgTb, wProj, nullptr,
                                                    nullptr, imgPb, 8192, 256, 256, 0);
    k_init_tgt<<<8192, 256, 0, stream>>>(tgt, tgtb, query_embed);

    for (int l = 0; l < 3; ++l) {
        // ---- self attention ----
        gemm_mfma<128><<<dim3(6, 64), 256, 0, stream>>>(tgtb, wSQKV + (size_t)l * 196608,
            self_qkv_b + (size_t)l * 768, Sbuf, nullptr, 8192, 768, 256, 0);
        k_self_attn<<<4096, 256, 0, stream>>>(Sbuf, Abuf);
        gemm_mfma<64><<<dim3(2, 128), 256, 0, stream>>>(Abuf, wSOut + (size_t)l * 65536,
            self_out_b + (size_t)l * 256, Pbuf, nullptr, 8192, 256, 256, 0);
        k_add_ln<<<2048, 256, 0, stream>>>(tgt, tgtb, Pbuf,
            ln1_w + (size_t)l * 256, ln1_b + (size_t)l * 256);

        // ---- cross attention ----
        gemm_mfma<64><<<dim3(2, 128), 256, 0, stream>>>(tgtb, wCQKV + (size_t)l * 196608,
            cross_qkv_b + (size_t)l * 768, Qbuf, nullptr, 8192, 256, 256, 0);
        gemm_mfma<128><<<dim3(4, 64), 256, 0, stream>>>(imgPb,
            wCQKV + (size_t)l * 196608 + 65536, nullptr,
            nullptr, KVb, 8192, 512, 256, 0);
        k_cross_attn<<<4096, 256, 0, stream>>>(Qbuf, KVb, ckv + (size_t)l * 512,
                                               valid, kps, Abuf);
        gemm_mfma<64><<<dim3(2, 128), 256, 0, stream>>>(Abuf, wCOut + (size_t)l * 65536,
            cross_out_b + (size_t)l * 256, Pbuf, nullptr, 8192, 256, 256, 0);
        k_add_ln<<<2048, 256, 0, stream>>>(tgt, tgtb, Pbuf,
            ln2_w + (size_t)l * 256, ln2_b + (size_t)l * 256);

        // ---- FFN ----
        gemm_mfma<128><<<dim3(8, 64), 256, 0, stream>>>(tgtb, wF1 + (size_t)l * 262144,
            ffn1_b + (size_t)l * 1024, nullptr, Hbuf, 8192, 1024, 256, 1);
        gemm_mfma<64><<<dim3(2, 128), 256, 0, stream>>>(Hbuf, wF2 + (size_t)l * 262144,
            ffn2_b + (size_t)l * 256, Pbuf, nullptr, 8192, 256, 1024, 0);
        k_add_ln<<<2048, 256, 0, stream>>>(tgt, tgtb, Pbuf,
            ln3_w + (size_t)l * 256, ln3_b + (size_t)l * 256);
    }

    k_out<<<128, 256, 0, stream>>>(tgt, out_w, out_b, out);
}

// Round 8
// 536.356 us; speedup vs baseline: 2.6134x; 1.1255x over previous
//
#include <hip/hip_runtime.h>
#include <hip/hip_fp16.h>

#define LB __launch_bounds__(256)

typedef unsigned short u16;
typedef unsigned int   u32;
typedef __attribute__((ext_vector_type(8))) short bf16x8;   // 8 bf16 (4 VGPRs)
typedef __attribute__((ext_vector_type(4))) float f32x4;
typedef __attribute__((ext_vector_type(8))) u16  u16x8;

__device__ __forceinline__ u16 f2b(float f) {
    u32 u = __float_as_uint(f);
    u32 r = (u + 0x7fffu + ((u >> 16) & 1u)) >> 16;
    return (u16)r;
}
__device__ __forceinline__ float b2f(u16 h) {
    return __uint_as_float((u32)h << 16);
}

// ---------------------------------------------------------------------------
// B=2 N=256 C=256 HF=WF=64 ROI=15(225) HID=256 HEADS=8 Dh=32 DEPTH=3 FFN=1024
// NQ=16 -> seqs S=512, MT=8192. Linearity: K = sample(imgP@Wk^T) + ckv.
// Cross-attn: verified sampling/softmax/masking + MFMA scores (Q[16,32]K^T)
// and MFMA PV (P[16,225]V) via transposed V scatter. Q now bf16.
// ---------------------------------------------------------------------------

// ---------- fused prep: mask dtype detect + per-layer ck/cv ----------------
__global__ void k_prep(const unsigned char* __restrict__ m, int* __restrict__ valid,
                       const float* __restrict__ pb,
                       const float* __restrict__ cqkv_w,
                       const float* __restrict__ cqkv_b,
                       float* __restrict__ ckv)
{
    if (blockIdx.x == 0) {
        __shared__ int flag;
        if (threadIdx.x == 0) flag = 0;
        __syncthreads();
        int loc = 0;
        for (int off = threadIdx.x; off < 512; off += 256)
            if ((off & 3) != 0 && m[off] != 0) loc = 1;
        if (loc) atomicOr(&flag, 1);
        __syncthreads();
        const bool bytelay = (flag != 0);
        for (int s = threadIdx.x; s < 512; s += 256)
            valid[s] = bytelay ? (int)(m[s] != 0) : (int)(((const int*)m)[s] != 0);
    } else {
        const int l = blockIdx.x - 1;   // 0..2
        const float* Wk = cqkv_w + (size_t)l * 196608 + 65536;
        const float* Wv = cqkv_w + (size_t)l * 196608 + 131072;
        const float* kb = cqkv_b + (size_t)l * 768 + 256;
        const float* vb = cqkv_b + (size_t)l * 768 + 512;
        const int o = threadIdx.x;
        float a = 0.f, c = 0.f;
        for (int cc = 0; cc < 256; cc += 4) {
            const float4 p4 = *(const float4*)(pb + cc);
            const float4 k4 = *(const float4*)(Wk + (size_t)o * 256 + cc);
            const float4 v4 = *(const float4*)(Wv + (size_t)o * 256 + cc);
            a += p4.x * k4.x + p4.y * k4.y + p4.z * k4.z + p4.w * k4.w;
            c += p4.x * v4.x + p4.y * v4.y + p4.z * v4.z + p4.w * v4.w;
        }
        ckv[l * 512 + o]       = a + kb[o];
        ckv[l * 512 + 256 + o] = c + vb[o];
    }
}

// ---------- weights fp32 -> bf16 arena -------------------------------------
__global__ LB void k_wconv(const float* __restrict__ s0, const float* __restrict__ s1,
                           const float* __restrict__ s2, const float* __restrict__ s3,
                           const float* __restrict__ s4, const float* __restrict__ s5,
                           const float* __restrict__ s6, u16* __restrict__ dst)
{
    const int e = blockIdx.x * 256 + threadIdx.x;
    if (e >= 3211264) return;
    float v;
    int i = e;
    if (i < 65536) v = s0[i];
    else if ((i -= 65536) < 589824) v = s1[i];
    else if ((i -= 589824) < 196608) v = s2[i];
    else if ((i -= 196608) < 589824) v = s3[i];
    else if ((i -= 589824) < 196608) v = s4[i];
    else if ((i -= 196608) < 786432) v = s5[i];
    else { i -= 786432; v = s6[i]; }
    dst[e] = f2b(v);
}

// ---------- transpose image (B,C,64,64) -> (B,4096,C) bf16 -----------------
__global__ LB void k_transpose(const float* __restrict__ img, u16* __restrict__ imgTb)
{
    __shared__ float tile[64][65];
    const int b  = blockIdx.z;
    const int c0 = blockIdx.y * 64;
    const int p0 = blockIdx.x * 64;
    const int t  = threadIdx.x;
    const int tr = t >> 6, tc = t & 63;
#pragma unroll
    for (int p = 0; p < 16; ++p) {
        const int i = p * 4 + tr;
        tile[i][tc] = img[((size_t)(b * 256 + c0 + i)) * 4096 + p0 + tc];
    }
    __syncthreads();
#pragma unroll
    for (int p = 0; p < 16; ++p) {
        const int jj = p * 4 + tr;
        imgTb[((size_t)(b * 4096 + p0 + jj)) * 256 + c0 + tc] = f2b(tile[tc][jj]);
    }
}

// ---------- bf16 MFMA GEMM: C[M,N] = A[M,K](bf16) @ W[N,K](bf16)^T + bias --
template<int BM>
__global__ LB void gemm_mfma(const u16* __restrict__ A, const u16* __restrict__ W,
                             const float* __restrict__ bias,
                             float* __restrict__ Cf, u16* __restrict__ Cb,
                             int M, int N, int K, int relu)
{
    constexpr int BN = 128;
    __shared__ u16 lds[2][(BM + BN) * 64];
    const int t = threadIdx.x;
    const int wid = t >> 6, lane = t & 63;
    const int bm = blockIdx.y * BM, bn = blockIdx.x * BN;
    const int KT = K >> 6;

    auto stage = [&](int buf, int kt) {
        const int k0 = kt * 64;
        const int rr = t >> 3;
        const int u  = t & 7;
#pragma unroll
        for (int q = 0; q < BM / 32; ++q) {
            const int r = q * 32 + rr;
            const u16* src = A + (size_t)(bm + r) * K + k0 + ((u ^ (r & 7)) << 3);
            __builtin_amdgcn_global_load_lds(
                (const __attribute__((address_space(1))) void*)src,
                (__attribute__((address_space(3))) void*)&lds[buf][q * 2048 + wid * 512],
                16, 0, 0);
        }
#pragma unroll
        for (int q = 0; q < 4; ++q) {
            const int r = q * 32 + rr;
            const u16* src = W + (size_t)(bn + r) * K + k0 + ((u ^ (r & 7)) << 3);
            __builtin_amdgcn_global_load_lds(
                (const __attribute__((address_space(1))) void*)src,
                (__attribute__((address_space(3))) void*)&lds[buf][BM * 64 + q * 2048 + wid * 512],
                16, 0, 0);
        }
    };

    const int wr = wid >> 1, wc = wid & 1;
    constexpr int MR = BM / 32;
    f32x4 acc[MR][4];
    const f32x4 z = {0.f, 0.f, 0.f, 0.f};
#pragma unroll
    for (int mi = 0; mi < MR; ++mi)
#pragma unroll
        for (int ni = 0; ni < 4; ++ni) acc[mi][ni] = z;

    const int r16 = lane & 15, kg = lane >> 4;

    stage(0, 0);
    int cur = 0;
    for (int kt = 0; kt < KT; ++kt) {
        asm volatile("s_waitcnt vmcnt(0)" ::: "memory");
        __syncthreads();
        if (kt + 1 < KT) stage(cur ^ 1, kt + 1);
        const u16* pA = lds[cur];
        const u16* pB = lds[cur] + BM * 64;
#pragma unroll
        for (int kk = 0; kk < 2; ++kk) {
            const int s = kk * 4 + kg;
            bf16x8 afr[MR], bfr[4];
#pragma unroll
            for (int mi = 0; mi < MR; ++mi) {
                const int r = wr * (BM / 2) + mi * 16 + r16;
                afr[mi] = *(const bf16x8*)(pA + r * 64 + ((s ^ (r & 7)) << 3));
            }
#pragma unroll
            for (int ni = 0; ni < 4; ++ni) {
                const int c = wc * 64 + ni * 16 + r16;
                bfr[ni] = *(const bf16x8*)(pB + c * 64 + ((s ^ (c & 7)) << 3));
            }
#pragma unroll
            for (int mi = 0; mi < MR; ++mi)
#pragma unroll
                for (int ni = 0; ni < 4; ++ni)
                    acc[mi][ni] = __builtin_amdgcn_mfma_f32_16x16x32_bf16(
                        afr[mi], bfr[ni], acc[mi][ni], 0, 0, 0);
        }
        cur ^= 1;
    }

#pragma unroll
    for (int mi = 0; mi < MR; ++mi) {
#pragma unroll
        for (int ni = 0; ni < 4; ++ni) {
            const int col = bn + wc * 64 + ni * 16 + r16;
            const float bs = bias ? bias[col] : 0.0f;
#pragma unroll
            for (int rg = 0; rg < 4; ++rg) {
                const int row = bm + wr * (BM / 2) + mi * 16 + kg * 4 + rg;
                float v = acc[mi][ni][rg] + bs;
                if (relu) v = fmaxf(v, 0.0f);
                if (Cf) Cf[(size_t)row * N + col] = v;
                if (Cb) Cb[(size_t)row * N + col] = f2b(v);
            }
        }
    }
}

// ---------- init tgt (fp32 + bf16) -----------------------------------------
__global__ LB void k_init_tgt(float* __restrict__ tgt, u16* __restrict__ tgtb,
                              const float* __restrict__ qe)
{
    const int e = blockIdx.x * 256 + threadIdx.x;
    const int c = e & 255;
    const int row = e >> 8;
    const int i = row & 15;
    const float v = qe[(i << 8) | c];
    tgt[e] = v;
    tgtb[e] = f2b(v);
}

// ---------- self attention: per (seq, head), 16q x 16k, Dh=32; out bf16 ----
__global__ LB void k_self_attn(const float* __restrict__ QKV, u16* __restrict__ O)
{
    const int blk = blockIdx.x;
    const int s = blk >> 3, h = blk & 7;
    __shared__ float q_s[16][36], k_s[16][36], v_s[16][36];
    __shared__ float e_s[16][17];
    __shared__ float rsum[16];
    const int t = threadIdx.x;
    const int i = t >> 4, j = t & 15;

    const float* basep = QKV + (size_t)(s * 16 + i) * 768 + h * 32;
    q_s[i][j]      = basep[j];
    q_s[i][j + 16] = basep[j + 16];
    k_s[i][j]      = basep[256 + j];
    k_s[i][j + 16] = basep[256 + j + 16];
    v_s[i][j]      = basep[512 + j];
    v_s[i][j + 16] = basep[512 + j + 16];
    __syncthreads();

    float acc = 0.0f;
#pragma unroll
    for (int d = 0; d < 32; d += 4) {
        const float4 q4 = *(const float4*)(&q_s[i][d]);
        const float4 k4 = *(const float4*)(&k_s[j][d]);
        acc += q4.x * k4.x + q4.y * k4.y + q4.z * k4.z + q4.w * k4.w;
    }
    const float sc = acc * 0.17677669529663687f;
    e_s[i][j] = sc;
    __syncthreads();
    float mx = e_s[i][0];
#pragma unroll
    for (int x = 1; x < 16; ++x) mx = fmaxf(mx, e_s[i][x]);
    const float e = __expf(sc - mx);
    __syncthreads();
    e_s[i][j] = e;
    __syncthreads();
    if (j == 0) {
        float sm = 0.0f;
#pragma unroll
        for (int x = 0; x < 16; ++x) sm += e_s[i][x];
        rsum[i] = sm;
    }
    __syncthreads();

    const int oi = t >> 5;
    const int d  = t & 31;
#pragma unroll
    for (int pass = 0; pass < 2; ++pass) {
        const int r = oi + pass * 8;
        float o = 0.0f;
#pragma unroll
        for (int x = 0; x < 16; ++x) o += e_s[r][x] * v_s[x][d];
        O[(size_t)(s * 16 + r) * 256 + h * 32 + d] = f2b(o / rsum[r]);
    }
}

// ---------- fused cross attention: sampling + MFMA scores/PV ---------------
// Qb bf16 [8192][256]; KV bf16 [B*4096][512] (K|V). Verified sampling/softmax;
// scores = mfma(Q[16,32], K-tile[16,32]); PV = mfma(P[16,256p], vT).
__global__ LB void k_cross_attn(const u16* __restrict__ Qb,
                                const u16* __restrict__ KV,
                                const float* __restrict__ ckv,
                                const int* __restrict__ valid,
                                const float* __restrict__ kps,
                                u16* __restrict__ O)
{
    const int blk = blockIdx.x;
    const int s = blk >> 3, h = blk & 7;
    const int b = s >> 8, n = s & 255;

    // ---- LDS arena (byte offsets; K-region and vT overlaid) ----
    __shared__ __align__(16) char arena[47904];
    u32*   taps  = (u32*)arena;               // [225][4]        0..3600
    u16*   kvu   = (u16*)(arena + 3600);      // K [225][40] / vT [32][264]
    u16*   q_b   = (u16*)(arena + 21600);     // [16][40]
    float* s2    = (float*)(arena + 22880);   // [16][240]
    float* o_prt = (float*)(arena + 22880);   // [2][16][32] (overlay, post-P)
    u16*   p_b   = (u16*)(arena + 38240);     // [16][264]
    float* red   = (float*)(arena + 46688);   // [16][17]
    float* rowm  = (float*)(arena + 47776);   // [16]
    float* rowsum= (float*)(arena + 47840);   // [16]

    const int t = threadIdx.x;
    const int i = t >> 4, jj = t & 15;
    const int lane = t & 63, wid = t >> 6;
    const int r16 = lane & 15, kg = lane >> 4;

    // ---- Q (bf16) into LDS [16][40] ----
    if (t < 64) {
        const int qi = t >> 2, c8q = (t & 3) * 8;
        *(u16x8*)(q_b + qi * 40 + c8q) =
            *(const u16x8*)(Qb + (size_t)(s * 16 + qi) * 256 + h * 32 + c8q);
    }

    // ---- taps (verified) ----
    if (t < 225) {
        const float kpy = kps[(b * 256 + n) * 2 + 0];
        const float kpx = kps[(b * 256 + n) * 2 + 1];
        const int iy = t / 15, ix = t - iy * 15;
        const float gy = rintf(kpy) + (float)(iy - 7);
        const float gx = rintf(kpx) + (float)(ix - 7);
        const float gxn = gx / 511.0f * 2.0f - 1.0f;
        const float gyn = gy / 511.0f * 2.0f - 1.0f;
        const bool inval = (gxn < -1.f) || (gyn < -1.f) || (gxn > 1.f) || (gyn > 1.f);
        const float x = ((gxn + 1.f) * 64.f - 1.f) * 0.5f;
        const float y = ((gyn + 1.f) * 64.f - 1.f) * 0.5f;
        const float x0f = floorf(x), y0f = floorf(y);
        const float wx = x - x0f, wy = y - y0f;
        const int x0 = (int)x0f, y0 = (int)y0f;
#pragma unroll
        for (int tt = 0; tt < 4; ++tt) {
            const int dy = tt >> 1, dx = tt & 1;
            const int yi = y0 + dy, xi = x0 + dx;
            const bool ok = (yi >= 0) && (yi < 64) && (xi >= 0) && (xi < 64) && !inval;
            const float w = (dy ? wy : 1.f - wy) * (dx ? wx : 1.f - wx);
            const u32 idx = ok ? (u32)(yi * 64 + xi) : 0u;
            const u16 hw = ok ? __half_as_ushort(__float2half_rn(w)) : (u16)0;
            taps[t * 4 + tt] = (idx << 16) | hw;
        }
    }
    const bool vld = valid[s] != 0;
    __syncthreads();

    const int rp = t >> 2;            // 0..63
    const int c8 = (t & 3) << 3;      // 0,8,16,24
    const u16* kvbase = KV + (size_t)b * 4096 * 512 + h * 32;

    // ---- sample K (+ck) row-major into kvu[225][40] (verified math) ----
    {
        float ck[8];
#pragma unroll
        for (int jx = 0; jx < 8; ++jx) ck[jx] = ckv[h * 32 + c8 + jx];
        for (int p0 = 0; p0 < 225; p0 += 64) {
            const int p = p0 + rp;
            if (p < 225) {
                float a[8];
#pragma unroll
                for (int jx = 0; jx < 8; ++jx) a[jx] = ck[jx];
#pragma unroll
                for (int tt = 0; tt < 4; ++tt) {
                    const u32 u = taps[p * 4 + tt];
                    const float w = __half2float(__ushort_as_half((u16)(u & 0xffffu)));
                    const u16x8 v = *(const u16x8*)(kvbase + (size_t)(u >> 16) * 512 + c8);
#pragma unroll
                    for (int jx = 0; jx < 8; ++jx) a[jx] += w * b2f(v[jx]);
                }
                u16x8 o;
#pragma unroll
                for (int jx = 0; jx < 8; ++jx) o[jx] = f2b(a[jx]);
                *(u16x8*)(kvu + p * 40 + c8) = o;
            }
        }
    }
    __syncthreads();

    // ---- scores via MFMA: S[16][225] = Q[16,32] @ K^T ----
    {
        const bf16x8 qfr = *(const bf16x8*)(q_b + r16 * 40 + kg * 8);
        for (int tile = wid; tile < 15; tile += 4) {
            const int row = tile * 16 + r16;           // K index j (may be >=225)
            const int rc = row < 225 ? row : 224;
            const bf16x8 kfr = *(const bf16x8*)(kvu + rc * 40 + kg * 8);
            f32x4 acc = {0.f, 0.f, 0.f, 0.f};
            acc = __builtin_amdgcn_mfma_f32_16x16x32_bf16(qfr, kfr, acc, 0, 0, 0);
#pragma unroll
            for (int rg = 0; rg < 4; ++rg) {
                const int qr = kg * 4 + rg;
                float sv = acc[rg] * 0.17677669529663687f;
                if (!vld && row > 0) sv = -1e30f;
                s2[qr * 240 + row] = sv;
            }
        }
    }
    __syncthreads();

    // ---- softmax over 225 per row (verified structure) ----
    float pm = -1e30f;
    for (int j = jj; j < 225; j += 16) pm = fmaxf(pm, s2[i * 240 + j]);
    red[i * 17 + jj] = pm;
    __syncthreads();
    if (t < 16) {
        float m = red[t * 17 + 0];
#pragma unroll
        for (int x = 1; x < 16; ++x) m = fmaxf(m, red[t * 17 + x]);
        rowm[t] = m;
    }
    __syncthreads();
    const float mx = rowm[i];
    float ps = 0.0f;
    for (int j = jj; j < 225; j += 16) {
        const float e = __expf(s2[i * 240 + j] - mx);
        s2[i * 240 + j] = e;
        ps += e;
    }
    red[i * 17 + jj] = ps;
    __syncthreads();
    if (t < 16) {
        float sm = 0.0f;
#pragma unroll
        for (int x = 0; x < 16; ++x) sm += red[t * 17 + x];
        rowsum[t] = sm;
    }
    __syncthreads();

    // ---- P -> bf16 [16][264], zero-padded to k=256 ----
    for (int e = t; e < 4096; e += 256) {             // 16 rows x 256 cols
        const int pi = e >> 8, pj = e & 255;
        p_b[pi * 264 + pj] = (pj < 225) ? f2b(s2[pi * 240 + pj]) : (u16)0;
    }

    // ---- zero vT pad cols [225,264), then sample V (+cv) transposed ----
    for (int e = t; e < 1248; e += 256) {             // 32 ch x 39 pad cols
        const int ch = e / 39, k = 225 + (e - ch * 39);
        kvu[ch * 264 + k] = 0;
    }
    {
        float cv[8];
#pragma unroll
        for (int jx = 0; jx < 8; ++jx) cv[jx] = ckv[256 + h * 32 + c8 + jx];
        for (int p0 = 0; p0 < 225; p0 += 64) {
            const int p = p0 + rp;
            if (p < 225) {
                float a[8];
#pragma unroll
                for (int jx = 0; jx < 8; ++jx) a[jx] = cv[jx];
#pragma unroll
                for (int tt = 0; tt < 4; ++tt) {
                    const u32 u = taps[p * 4 + tt];
                    const float w = __half2float(__ushort_as_half((u16)(u & 0xffffu)));
                    const u16x8 v = *(const u16x8*)(kvbase + 256 + (size_t)(u >> 16) * 512 + c8);
#pragma unroll
                    for (int jx = 0; jx < 8; ++jx) a[jx] += w * b2f(v[jx]);
                }
#pragma unroll
                for (int jx = 0; jx < 8; ++jx)
                    kvu[(c8 + jx) * 264 + p] = f2b(a[jx]);   // vT[ch][p]
            }
        }
    }
    __syncthreads();

    // ---- PV via MFMA: O[16,32] = P[16,256p] @ V; 4 waves = 2 ch-tiles x 2 k-halves
    {
        const int ct = wid & 1, kh = wid >> 1;
        f32x4 acc2 = {0.f, 0.f, 0.f, 0.f};
#pragma unroll
        for (int q = 0; q < 4; ++q) {
            const int ks = kh * 4 + q;
            const bf16x8 pa = *(const bf16x8*)(p_b + r16 * 264 + ks * 32 + kg * 8);
            const bf16x8 vb = *(const bf16x8*)(kvu + (ct * 16 + r16) * 264 + ks * 32 + kg * 8);
            acc2 = __builtin_amdgcn_mfma_f32_16x16x32_bf16(pa, vb, acc2, 0, 0, 0);
        }
#pragma unroll
        for (int rg = 0; rg < 4; ++rg)
            o_prt[kh * 512 + (kg * 4 + rg) * 32 + ct * 16 + r16] = acc2[rg];
    }
    __syncthreads();

    // ---- combine halves, normalize, write (verified output mapping) ----
    {
        const int d0 = jj * 2;
        const float inv = 1.0f / rowsum[i];
        const float o0 = (o_prt[i * 32 + d0]     + o_prt[512 + i * 32 + d0])     * inv;
        const float o1 = (o_prt[i * 32 + d0 + 1] + o_prt[512 + i * 32 + d0 + 1]) * inv;
        const u32 ob = (u32)f2b(o0) | ((u32)f2b(o1) << 16);
        *(u32*)(O + (size_t)(s * 16 + i) * 256 + h * 32 + d0) = ob;
    }
}

// ---------- residual add + LayerNorm; writes fp32 X and bf16 Xb ------------
__global__ LB void k_add_ln(float* __restrict__ X, u16* __restrict__ Xb,
                            const float* __restrict__ D,
                            const float* __restrict__ w, const float* __restrict__ b)
{
    const int row  = blockIdx.x * 4 + (threadIdx.x >> 6);
    const int lane = threadIdx.x & 63;
    float4 x = ((const float4*)(X + (size_t)row * 256))[lane];
    const float4 d = ((const float4*)(D + (size_t)row * 256))[lane];
    x.x += d.x; x.y += d.y; x.z += d.z; x.w += d.w;
    float s = x.x + x.y + x.z + x.w;
#pragma unroll
    for (int m = 1; m < 64; m <<= 1) s += __shfl_xor(s, m);
    const float mu = s * (1.0f / 256.0f);
    const float4 c = make_float4(x.x - mu, x.y - mu, x.z - mu, x.w - mu);
    float q = c.x * c.x + c.y * c.y + c.z * c.z + c.w * c.w;
#pragma unroll
    for (int m = 1; m < 64; m <<= 1) q += __shfl_xor(q, m);
    const float inv = 1.0f / sqrtf(q * (1.0f / 256.0f) + 1e-5f);
    const float4 w4 = ((const float4*)w)[lane];
    const float4 b4 = ((const float4*)b)[lane];
    float4 o;
    o.x = c.x * inv * w4.x + b4.x;
    o.y = c.y * inv * w4.y + b4.y;
    o.z = c.z * inv * w4.z + b4.z;
    o.w = c.w * inv * w4.w + b4.w;
    ((float4*)(X + (size_t)row * 256))[lane] = o;
    ushort4 ob;
    ob.x = f2b(o.x); ob.y = f2b(o.y); ob.z = f2b(o.z); ob.w = f2b(o.w);
    ((ushort4*)(Xb + (size_t)row * 256))[lane] = ob;
}

// ---------- output head: (8192,256) @ (4,256)^T + b ------------------------
__global__ LB void k_out(const float* __restrict__ X, const float* __restrict__ W,
                         const float* __restrict__ bias, float* __restrict__ O)
{
    __shared__ float w_s[4][260];
    const int t = threadIdx.x;
    for (int e = t; e < 1024; e += 256) w_s[e >> 8][e & 255] = W[e];
    __syncthreads();
    const int row = blockIdx.x * 64 + (t >> 2);
    const int j = t & 3;
    const float4* xr = (const float4*)(X + (size_t)row * 256);
    float acc = 0.0f;
#pragma unroll
    for (int k4 = 0; k4 < 64; ++k4) {
        const float4 x = xr[k4];
        acc += x.x * w_s[j][k4 * 4]     + x.y * w_s[j][k4 * 4 + 1]
             + x.z * w_s[j][k4 * 4 + 2] + x.w * w_s[j][k4 * 4 + 3];
    }
    O[(size_t)row * 4 + j] = acc + bias[j];
}

// ---------------------------------------------------------------------------
extern "C" void kernel_launch(void* const* d_in, const int* in_sizes, int n_in,
                              void* d_out, int out_size, void* d_ws, size_t ws_size,
                              hipStream_t stream)
{
    const float* img          = (const float*)d_in[0];
    const float* kps          = (const float*)d_in[1];
    const unsigned char* vmsk = (const unsigned char*)d_in[2];
    const float* proj_w       = (const float*)d_in[3];
    const float* proj_b       = (const float*)d_in[4];
    const float* query_embed  = (const float*)d_in[5];
    const float* self_qkv_w   = (const float*)d_in[6];
    const float* self_qkv_b   = (const float*)d_in[7];
    const float* self_out_w   = (const float*)d_in[8];
    const float* self_out_b   = (const float*)d_in[9];
    const float* cross_qkv_w  = (const float*)d_in[10];
    const float* cross_qkv_b  = (const float*)d_in[11];
    const float* cross_out_w  = (const float*)d_in[12];
    const float* cross_out_b  = (const float*)d_in[13];
    const float* ffn1_w       = (const float*)d_in[14];
    const float* ffn1_b       = (const float*)d_in[15];
    const float* ffn2_w       = (const float*)d_in[16];
    const float* ffn2_b       = (const float*)d_in[17];
    const float* ln1_w        = (const float*)d_in[18];
    const float* ln1_b        = (const float*)d_in[19];
    const float* ln2_w        = (const float*)d_in[20];
    const float* ln2_b        = (const float*)d_in[21];
    const float* ln3_w        = (const float*)d_in[22];
    const float* ln3_b        = (const float*)d_in[23];
    const float* out_w        = (const float*)d_in[24];
    const float* out_b        = (const float*)d_in[25];
    float* out = (float*)d_out;

    // ---- workspace layout ----
    char* W8 = (char*)d_ws;
    size_t off = 0;
    auto alloc = [&](size_t bytes) { void* p = W8 + off; off += (bytes + 255) & ~(size_t)255; return p; };
    float* tgt   = (float*)alloc(2097152 * 4);
    float* Qbuf  = (float*)alloc(2097152 * 4);   // low half reused as bf16 Qb
    float* Pbuf  = (float*)alloc(2097152 * 4);
    float* Sbuf  = (float*)alloc(6291456 * 4);
    float* ckv   = (float*)alloc(3 * 512 * 4);
    u16* imgTb   = (u16*)alloc(2097152 * 2);
    u16* imgPb   = (u16*)alloc(2097152 * 2);
    u16* KVb     = (u16*)alloc(4194304 * 2);
    u16* tgtb    = (u16*)alloc(2097152 * 2);
    u16* Abuf    = (u16*)alloc(2097152 * 2);
    u16* Hbuf    = (u16*)alloc(8388608 * 2);
    u16* wAll    = (u16*)alloc(3211264 * 2);
    int* valid   = (int*)alloc(512 * 4);
    u16* Qb = (u16*)Qbuf;

    u16* wProj = wAll;             // 65536
    u16* wSQKV = wProj + 65536;    // 3*768*256
    u16* wSOut = wSQKV + 589824;   // 3*256*256
    u16* wCQKV = wSOut + 196608;   // 3*768*256
    u16* wCOut = wCQKV + 589824;   // 3*256*256
    u16* wF1   = wCOut + 196608;   // 3*1024*256
    u16* wF2   = wF1 + 786432;     // 3*256*1024

    k_prep<<<4, 256, 0, stream>>>(vmsk, valid, proj_b, cross_qkv_w, cross_qkv_b, ckv);
    k_wconv<<<12544, 256, 0, stream>>>(proj_w, self_qkv_w, self_out_w, cross_qkv_w,
                                       cross_out_w, ffn1_w, ffn2_w, wAll);
    k_transpose<<<dim3(64, 4, 2), 256, 0, stream>>>(img, imgTb);
    gemm_mfma<64><<<dim3(2, 128), 256, 0, stream>>>(imgTb, wProj, nullptr,
                                                    nullptr, imgPb, 8192, 256, 256, 0);
    k_init_tgt<<<8192, 256, 0, stream>>>(tgt, tgtb, query_embed);

    for (int l = 0; l < 3; ++l) {
        // ---- self attention ----
        gemm_mfma<128><<<dim3(6, 64), 256, 0, stream>>>(tgtb, wSQKV + (size_t)l * 196608,
            self_qkv_b + (size_t)l * 768, Sbuf, nullptr, 8192, 768, 256, 0);
        k_self_attn<<<4096, 256, 0, stream>>>(Sbuf, Abuf);
        gemm_mfma<64><<<dim3(2, 128), 256, 0, stream>>>(Abuf, wSOut + (size_t)l * 65536,
            self_out_b + (size_t)l * 256, Pbuf, nullptr, 8192, 256, 256, 0);
        k_add_ln<<<2048, 256, 0, stream>>>(tgt, tgtb, Pbuf,
            ln1_w + (size_t)l * 256, ln1_b + (size_t)l * 256);

        // ---- cross attention ----
        gemm_mfma<64><<<dim3(2, 128), 256, 0, stream>>>(tgtb, wCQKV + (size_t)l * 196608,
            cross_qkv_b + (size_t)l * 768, nullptr, Qb, 8192, 256, 256, 0);
        gemm_mfma<128><<<dim3(4, 64), 256, 0, stream>>>(imgPb,
            wCQKV + (size_t)l * 196608 + 65536, nullptr,
            nullptr, KVb, 8192, 512, 256, 0);
        k_cross_attn<<<4096, 256, 0, stream>>>(Qb, KVb, ckv + (size_t)l * 512,
                                               valid, kps, Abuf);
        gemm_mfma<64><<<dim3(2, 128), 256, 0, stream>>>(Abuf, wCOut + (size_t)l * 65536,
            cross_out_b + (size_t)l * 256, Pbuf, nullptr, 8192, 256, 256, 0);
        k_add_ln<<<2048, 256, 0, stream>>>(tgt, tgtb, Pbuf,
            ln2_w + (size_t)l * 256, ln2_b + (size_t)l * 256);

        // ---- FFN ----
        gemm_mfma<128><<<dim3(8, 64), 256, 0, stream>>>(tgtb, wF1 + (size_t)l * 262144,
            ffn1_b + (size_t)l * 1024, nullptr, Hbuf, 8192, 1024, 256, 1);
        gemm_mfma<64><<<dim3(2, 128), 256, 0, stream>>>(Hbuf, wF2 + (size_t)l * 262144,
            ffn2_b + (size_t)l * 256, Pbuf, nullptr, 8192, 256, 1024, 0);
        k_add_ln<<<2048, 256, 0, stream>>>(tgt, tgtb, Pbuf,
            ln3_w + (size_t)l * 256, ln3_b + (size_t)l * 256);
    }

    k_out<<<128, 256, 0, stream>>>(tgt, out_w, out_b, out);
}

// Round 9
// 524.029 us; speedup vs baseline: 2.6749x; 1.0235x over previous
//
#include <hip/hip_runtime.h>
#include <hip/hip_fp16.h>

#define LB __launch_bounds__(256)

typedef unsigned short u16;
typedef unsigned int   u32;
typedef __attribute__((ext_vector_type(8))) short bf16x8;   // 8 bf16 (4 VGPRs)
typedef __attribute__((ext_vector_type(4))) float f32x4;
typedef __attribute__((ext_vector_type(8))) u16  u16x8;

__device__ __forceinline__ u16 f2b(float f) {
    u32 u = __float_as_uint(f);
    u32 r = (u + 0x7fffu + ((u >> 16) & 1u)) >> 16;
    return (u16)r;
}
__device__ __forceinline__ float b2f(u16 h) {
    return __uint_as_float((u32)h << 16);
}

// ---------------------------------------------------------------------------
// B=2 N=256 C=256 HF=WF=64 ROI=15(225) HID=256 HEADS=8 Dh=32 DEPTH=3 FFN=1024
// NQ=16 -> seqs S=512, MT=8192. Linearity: K = sample(imgP@Wk^T) + ckv.
// Cross-attn: MFMA scores/PV; LDS slimmed to <40KB (4 blocks/CU) via
// s2/(p_b+o_prt) overlay; vT scatter de-conflicted by jx rotation.
// ---------------------------------------------------------------------------

// ---------- fused prep: mask dtype detect + per-layer ck/cv ----------------
__global__ void k_prep(const unsigned char* __restrict__ m, int* __restrict__ valid,
                       const float* __restrict__ pb,
                       const float* __restrict__ cqkv_w,
                       const float* __restrict__ cqkv_b,
                       float* __restrict__ ckv)
{
    if (blockIdx.x == 0) {
        __shared__ int flag;
        if (threadIdx.x == 0) flag = 0;
        __syncthreads();
        int loc = 0;
        for (int off = threadIdx.x; off < 512; off += 256)
            if ((off & 3) != 0 && m[off] != 0) loc = 1;
        if (loc) atomicOr(&flag, 1);
        __syncthreads();
        const bool bytelay = (flag != 0);
        for (int s = threadIdx.x; s < 512; s += 256)
            valid[s] = bytelay ? (int)(m[s] != 0) : (int)(((const int*)m)[s] != 0);
    } else {
        const int l = blockIdx.x - 1;   // 0..2
        const float* Wk = cqkv_w + (size_t)l * 196608 + 65536;
        const float* Wv = cqkv_w + (size_t)l * 196608 + 131072;
        const float* kb = cqkv_b + (size_t)l * 768 + 256;
        const float* vb = cqkv_b + (size_t)l * 768 + 512;
        const int o = threadIdx.x;
        float a = 0.f, c = 0.f;
        for (int cc = 0; cc < 256; cc += 4) {
            const float4 p4 = *(const float4*)(pb + cc);
            const float4 k4 = *(const float4*)(Wk + (size_t)o * 256 + cc);
            const float4 v4 = *(const float4*)(Wv + (size_t)o * 256 + cc);
            a += p4.x * k4.x + p4.y * k4.y + p4.z * k4.z + p4.w * k4.w;
            c += p4.x * v4.x + p4.y * v4.y + p4.z * v4.z + p4.w * v4.w;
        }
        ckv[l * 512 + o]       = a + kb[o];
        ckv[l * 512 + 256 + o] = c + vb[o];
    }
}

// ---------- weights fp32 -> bf16 arena -------------------------------------
__global__ LB void k_wconv(const float* __restrict__ s0, const float* __restrict__ s1,
                           const float* __restrict__ s2, const float* __restrict__ s3,
                           const float* __restrict__ s4, const float* __restrict__ s5,
                           const float* __restrict__ s6, u16* __restrict__ dst)
{
    const int e = blockIdx.x * 256 + threadIdx.x;
    if (e >= 3211264) return;
    float v;
    int i = e;
    if (i < 65536) v = s0[i];
    else if ((i -= 65536) < 589824) v = s1[i];
    else if ((i -= 589824) < 196608) v = s2[i];
    else if ((i -= 196608) < 589824) v = s3[i];
    else if ((i -= 589824) < 196608) v = s4[i];
    else if ((i -= 196608) < 786432) v = s5[i];
    else { i -= 786432; v = s6[i]; }
    dst[e] = f2b(v);
}

// ---------- transpose image (B,C,64,64) -> (B,4096,C) bf16 -----------------
__global__ LB void k_transpose(const float* __restrict__ img, u16* __restrict__ imgTb)
{
    __shared__ float tile[64][65];
    const int b  = blockIdx.z;
    const int c0 = blockIdx.y * 64;
    const int p0 = blockIdx.x * 64;
    const int t  = threadIdx.x;
    const int tr = t >> 6, tc = t & 63;
#pragma unroll
    for (int p = 0; p < 16; ++p) {
        const int i = p * 4 + tr;
        tile[i][tc] = img[((size_t)(b * 256 + c0 + i)) * 4096 + p0 + tc];
    }
    __syncthreads();
#pragma unroll
    for (int p = 0; p < 16; ++p) {
        const int jj = p * 4 + tr;
        imgTb[((size_t)(b * 4096 + p0 + jj)) * 256 + c0 + tc] = f2b(tile[tc][jj]);
    }
}

// ---------- bf16 MFMA GEMM: C[M,N] = A[M,K](bf16) @ W[N,K](bf16)^T + bias --
template<int BM>
__global__ LB void gemm_mfma(const u16* __restrict__ A, const u16* __restrict__ W,
                             const float* __restrict__ bias,
                             float* __restrict__ Cf, u16* __restrict__ Cb,
                             int M, int N, int K, int relu)
{
    constexpr int BN = 128;
    __shared__ u16 lds[2][(BM + BN) * 64];
    const int t = threadIdx.x;
    const int wid = t >> 6, lane = t & 63;
    const int bm = blockIdx.y * BM, bn = blockIdx.x * BN;
    const int KT = K >> 6;

    auto stage = [&](int buf, int kt) {
        const int k0 = kt * 64;
        const int rr = t >> 3;
        const int u  = t & 7;
#pragma unroll
        for (int q = 0; q < BM / 32; ++q) {
            const int r = q * 32 + rr;
            const u16* src = A + (size_t)(bm + r) * K + k0 + ((u ^ (r & 7)) << 3);
            __builtin_amdgcn_global_load_lds(
                (const __attribute__((address_space(1))) void*)src,
                (__attribute__((address_space(3))) void*)&lds[buf][q * 2048 + wid * 512],
                16, 0, 0);
        }
#pragma unroll
        for (int q = 0; q < 4; ++q) {
            const int r = q * 32 + rr;
            const u16* src = W + (size_t)(bn + r) * K + k0 + ((u ^ (r & 7)) << 3);
            __builtin_amdgcn_global_load_lds(
                (const __attribute__((address_space(1))) void*)src,
                (__attribute__((address_space(3))) void*)&lds[buf][BM * 64 + q * 2048 + wid * 512],
                16, 0, 0);
        }
    };

    const int wr = wid >> 1, wc = wid & 1;
    constexpr int MR = BM / 32;
    f32x4 acc[MR][4];
    const f32x4 z = {0.f, 0.f, 0.f, 0.f};
#pragma unroll
    for (int mi = 0; mi < MR; ++mi)
#pragma unroll
        for (int ni = 0; ni < 4; ++ni) acc[mi][ni] = z;

    const int r16 = lane & 15, kg = lane >> 4;

    stage(0, 0);
    int cur = 0;
    for (int kt = 0; kt < KT; ++kt) {
        asm volatile("s_waitcnt vmcnt(0)" ::: "memory");
        __syncthreads();
        if (kt + 1 < KT) stage(cur ^ 1, kt + 1);
        const u16* pA = lds[cur];
        const u16* pB = lds[cur] + BM * 64;
#pragma unroll
        for (int kk = 0; kk < 2; ++kk) {
            const int s = kk * 4 + kg;
            bf16x8 afr[MR], bfr[4];
#pragma unroll
            for (int mi = 0; mi < MR; ++mi) {
                const int r = wr * (BM / 2) + mi * 16 + r16;
                afr[mi] = *(const bf16x8*)(pA + r * 64 + ((s ^ (r & 7)) << 3));
            }
#pragma unroll
            for (int ni = 0; ni < 4; ++ni) {
                const int c = wc * 64 + ni * 16 + r16;
                bfr[ni] = *(const bf16x8*)(pB + c * 64 + ((s ^ (c & 7)) << 3));
            }
#pragma unroll
            for (int mi = 0; mi < MR; ++mi)
#pragma unroll
                for (int ni = 0; ni < 4; ++ni)
                    acc[mi][ni] = __builtin_amdgcn_mfma_f32_16x16x32_bf16(
                        afr[mi], bfr[ni], acc[mi][ni], 0, 0, 0);
        }
        cur ^= 1;
    }

#pragma unroll
    for (int mi = 0; mi < MR; ++mi) {
#pragma unroll
        for (int ni = 0; ni < 4; ++ni) {
            const int col = bn + wc * 64 + ni * 16 + r16;
            const float bs = bias ? bias[col] : 0.0f;
#pragma unroll
            for (int rg = 0; rg < 4; ++rg) {
                const int row = bm + wr * (BM / 2) + mi * 16 + kg * 4 + rg;
                float v = acc[mi][ni][rg] + bs;
                if (relu) v = fmaxf(v, 0.0f);
                if (Cf) Cf[(size_t)row * N + col] = v;
                if (Cb) Cb[(size_t)row * N + col] = f2b(v);
            }
        }
    }
}

// ---------- init tgt (fp32 + bf16) -----------------------------------------
__global__ LB void k_init_tgt(float* __restrict__ tgt, u16* __restrict__ tgtb,
                              const float* __restrict__ qe)
{
    const int e = blockIdx.x * 256 + threadIdx.x;
    const int c = e & 255;
    const int row = e >> 8;
    const int i = row & 15;
    const float v = qe[(i << 8) | c];
    tgt[e] = v;
    tgtb[e] = f2b(v);
}

// ---------- self attention: per (seq, head), 16q x 16k, Dh=32; out bf16 ----
__global__ LB void k_self_attn(const float* __restrict__ QKV, u16* __restrict__ O)
{
    const int blk = blockIdx.x;
    const int s = blk >> 3, h = blk & 7;
    __shared__ float q_s[16][36], k_s[16][36], v_s[16][36];
    __shared__ float e_s[16][17];
    __shared__ float rsum[16];
    const int t = threadIdx.x;
    const int i = t >> 4, j = t & 15;

    const float* basep = QKV + (size_t)(s * 16 + i) * 768 + h * 32;
    q_s[i][j]      = basep[j];
    q_s[i][j + 16] = basep[j + 16];
    k_s[i][j]      = basep[256 + j];
    k_s[i][j + 16] = basep[256 + j + 16];
    v_s[i][j]      = basep[512 + j];
    v_s[i][j + 16] = basep[512 + j + 16];
    __syncthreads();

    float acc = 0.0f;
#pragma unroll
    for (int d = 0; d < 32; d += 4) {
        const float4 q4 = *(const float4*)(&q_s[i][d]);
        const float4 k4 = *(const float4*)(&k_s[j][d]);
        acc += q4.x * k4.x + q4.y * k4.y + q4.z * k4.z + q4.w * k4.w;
    }
    const float sc = acc * 0.17677669529663687f;
    e_s[i][j] = sc;
    __syncthreads();
    float mx = e_s[i][0];
#pragma unroll
    for (int x = 1; x < 16; ++x) mx = fmaxf(mx, e_s[i][x]);
    const float e = __expf(sc - mx);
    __syncthreads();
    e_s[i][j] = e;
    __syncthreads();
    if (j == 0) {
        float sm = 0.0f;
#pragma unroll
        for (int x = 0; x < 16; ++x) sm += e_s[i][x];
        rsum[i] = sm;
    }
    __syncthreads();

    const int oi = t >> 5;
    const int d  = t & 31;
#pragma unroll
    for (int pass = 0; pass < 2; ++pass) {
        const int r = oi + pass * 8;
        float o = 0.0f;
#pragma unroll
        for (int x = 0; x < 16; ++x) o += e_s[r][x] * v_s[x][d];
        O[(size_t)(s * 16 + r) * 256 + h * 32 + d] = f2b(o / rsum[r]);
    }
}

// ---------- fused cross attention: sampling + MFMA scores/PV ---------------
// Qb bf16 [8192][256]; KV bf16 [B*4096][512] (K|V). LDS 39456 B -> 4 blk/CU.
__global__ LB void k_cross_attn(const u16* __restrict__ Qb,
                                const u16* __restrict__ KV,
                                const float* __restrict__ ckv,
                                const int* __restrict__ valid,
                                const float* __restrict__ kps,
                                u16* __restrict__ O)
{
    const int blk = blockIdx.x;
    const int s = blk >> 3, h = blk & 7;
    const int b = s >> 8, n = s & 255;

    // ---- LDS arena 39456 B ----
    //  taps 0..3600 | kvu 3600..21600 (K [225][40] / vT [32][264])
    //  q_b 21600..22880 | R=22880..38240: s2 [16][240] f32, then overlay
    //  p_b [16][264] bf16 (R..R+8448) + o_prt [2][16][32] f32 (R+8448..R+12544)
    //  red 38240..39328 | rowm 39328 | rowsum 39392
    __shared__ __align__(16) char arena[39456];
    u32*   taps  = (u32*)arena;
    u16*   kvu   = (u16*)(arena + 3600);
    u16*   q_b   = (u16*)(arena + 21600);
    float* s2    = (float*)(arena + 22880);
    u16*   p_b   = (u16*)(arena + 22880);     // overlays s2 (dead after stage)
    float* o_prt = (float*)(arena + 31328);   // 22880 + 8448
    float* red   = (float*)(arena + 38240);
    float* rowm  = (float*)(arena + 39328);
    float* rowsum= (float*)(arena + 39392);

    const int t = threadIdx.x;
    const int i = t >> 4, jj = t & 15;
    const int lane = t & 63, wid = t >> 6;
    const int r16 = lane & 15, kg = lane >> 4;

    // ---- Q (bf16) into LDS [16][40] ----
    if (t < 64) {
        const int qi = t >> 2, c8q = (t & 3) * 8;
        *(u16x8*)(q_b + qi * 40 + c8q) =
            *(const u16x8*)(Qb + (size_t)(s * 16 + qi) * 256 + h * 32 + c8q);
    }

    // ---- taps (verified) ----
    if (t < 225) {
        const float kpy = kps[(b * 256 + n) * 2 + 0];
        const float kpx = kps[(b * 256 + n) * 2 + 1];
        const int iy = t / 15, ix = t - iy * 15;
        const float gy = rintf(kpy) + (float)(iy - 7);
        const float gx = rintf(kpx) + (float)(ix - 7);
        const float gxn = gx / 511.0f * 2.0f - 1.0f;
        const float gyn = gy / 511.0f * 2.0f - 1.0f;
        const bool inval = (gxn < -1.f) || (gyn < -1.f) || (gxn > 1.f) || (gyn > 1.f);
        const float x = ((gxn + 1.f) * 64.f - 1.f) * 0.5f;
        const float y = ((gyn + 1.f) * 64.f - 1.f) * 0.5f;
        const float x0f = floorf(x), y0f = floorf(y);
        const float wx = x - x0f, wy = y - y0f;
        const int x0 = (int)x0f, y0 = (int)y0f;
#pragma unroll
        for (int tt = 0; tt < 4; ++tt) {
            const int dy = tt >> 1, dx = tt & 1;
            const int yi = y0 + dy, xi = x0 + dx;
            const bool ok = (yi >= 0) && (yi < 64) && (xi >= 0) && (xi < 64) && !inval;
            const float w = (dy ? wy : 1.f - wy) * (dx ? wx : 1.f - wx);
            const u32 idx = ok ? (u32)(yi * 64 + xi) : 0u;
            const u16 hw = ok ? __half_as_ushort(__float2half_rn(w)) : (u16)0;
            taps[t * 4 + tt] = (idx << 16) | hw;
        }
    }
    const bool vld = valid[s] != 0;
    __syncthreads();

    const int rp = t >> 2;            // 0..63
    const int c8 = (t & 3) << 3;      // 0,8,16,24
    const u16* kvbase = KV + (size_t)b * 4096 * 512 + h * 32;

    // ---- sample K (+ck) row-major into kvu[225][40] (verified math) ----
    {
        float ck[8];
#pragma unroll
        for (int jx = 0; jx < 8; ++jx) ck[jx] = ckv[h * 32 + c8 + jx];
        for (int p0 = 0; p0 < 225; p0 += 64) {
            const int p = p0 + rp;
            if (p < 225) {
                float a[8];
#pragma unroll
                for (int jx = 0; jx < 8; ++jx) a[jx] = ck[jx];
#pragma unroll
                for (int tt = 0; tt < 4; ++tt) {
                    const u32 u = taps[p * 4 + tt];
                    const float w = __half2float(__ushort_as_half((u16)(u & 0xffffu)));
                    const u16x8 v = *(const u16x8*)(kvbase + (size_t)(u >> 16) * 512 + c8);
#pragma unroll
                    for (int jx = 0; jx < 8; ++jx) a[jx] += w * b2f(v[jx]);
                }
                u16x8 o;
#pragma unroll
                for (int jx = 0; jx < 8; ++jx) o[jx] = f2b(a[jx]);
                *(u16x8*)(kvu + p * 40 + c8) = o;
            }
        }
    }
    __syncthreads();

    // ---- scores via MFMA: S[16][225] = Q[16,32] @ K^T ----
    {
        const bf16x8 qfr = *(const bf16x8*)(q_b + r16 * 40 + kg * 8);
        for (int tile = wid; tile < 15; tile += 4) {
            const int row = tile * 16 + r16;           // K index j
            const int rc = row < 225 ? row : 224;
            const bf16x8 kfr = *(const bf16x8*)(kvu + rc * 40 + kg * 8);
            f32x4 acc = {0.f, 0.f, 0.f, 0.f};
            acc = __builtin_amdgcn_mfma_f32_16x16x32_bf16(qfr, kfr, acc, 0, 0, 0);
#pragma unroll
            for (int rg = 0; rg < 4; ++rg) {
                const int qr = kg * 4 + rg;
                float sv = acc[rg] * 0.17677669529663687f;
                if (!vld && row > 0) sv = -1e30f;
                s2[qr * 240 + row] = sv;
            }
        }
    }
    __syncthreads();

    // ---- softmax over 225 per row (verified structure) ----
    float pm = -1e30f;
    for (int j = jj; j < 225; j += 16) pm = fmaxf(pm, s2[i * 240 + j]);
    red[i * 17 + jj] = pm;
    __syncthreads();
    if (t < 16) {
        float m = red[t * 17 + 0];
#pragma unroll
        for (int x = 1; x < 16; ++x) m = fmaxf(m, red[t * 17 + x]);
        rowm[t] = m;
    }
    __syncthreads();
    const float mx = rowm[i];
    float ps = 0.0f;
    for (int j = jj; j < 225; j += 16) {
        const float e = __expf(s2[i * 240 + j] - mx);
        s2[i * 240 + j] = e;
        ps += e;
    }
    red[i * 17 + jj] = ps;
    __syncthreads();
    if (t < 16) {
        float sm = 0.0f;
#pragma unroll
        for (int x = 0; x < 16; ++x) sm += red[t * 17 + x];
        rowsum[t] = sm;
    }
    __syncthreads();

    // ---- P -> registers (thread t owns column t), then overlay-write bf16 --
    float pv[16];
#pragma unroll
    for (int pi = 0; pi < 16; ++pi)
        pv[pi] = (t < 225) ? s2[pi * 240 + t] : 0.0f;
    __syncthreads();                   // all s2 reads done before overlay write
#pragma unroll
    for (int pi = 0; pi < 16; ++pi)
        p_b[pi * 264 + t] = f2b(pv[pi]);

    // ---- zero vT pad cols [225,264), then sample V (+cv) transposed -------
    for (int e = t; e < 1248; e += 256) {             // 32 ch x 39 pad cols
        const int ch = e / 39, k = 225 + (e - ch * 39);
        kvu[ch * 264 + k] = 0;
    }
    {
        const int rot = (t & 3) * 2;   // de-conflict: stagger row order per c8
        float cv[8];
#pragma unroll
        for (int jx = 0; jx < 8; ++jx) cv[jx] = ckv[256 + h * 32 + c8 + jx];
        for (int p0 = 0; p0 < 225; p0 += 64) {
            const int p = p0 + rp;
            if (p < 225) {
                float a[8];
#pragma unroll
                for (int jx = 0; jx < 8; ++jx) a[jx] = cv[jx];
#pragma unroll
                for (int tt = 0; tt < 4; ++tt) {
                    const u32 u = taps[p * 4 + tt];
                    const float w = __half2float(__ushort_as_half((u16)(u & 0xffffu)));
                    const u16x8 v = *(const u16x8*)(kvbase + 256 + (size_t)(u >> 16) * 512 + c8);
#pragma unroll
                    for (int jx = 0; jx < 8; ++jx) a[jx] += w * b2f(v[jx]);
                }
#pragma unroll
                for (int jx = 0; jx < 8; ++jx) {
                    const int jxr = (jx + rot) & 7;
                    kvu[(c8 + jxr) * 264 + p] = f2b(a[jxr]);   // vT[ch][p]
                }
            }
        }
    }
    __syncthreads();

    // ---- PV via MFMA: O[16,32] = P[16,256p] @ V; 4 waves = 2 ch x 2 k-halves
    {
        const int ct = wid & 1, kh = wid >> 1;
        f32x4 acc2 = {0.f, 0.f, 0.f, 0.f};
#pragma unroll
        for (int q = 0; q < 4; ++q) {
            const int ks = kh * 4 + q;
            const bf16x8 pa = *(const bf16x8*)(p_b + r16 * 264 + ks * 32 + kg * 8);
            const bf16x8 vb = *(const bf16x8*)(kvu + (ct * 16 + r16) * 264 + ks * 32 + kg * 8);
            acc2 = __builtin_amdgcn_mfma_f32_16x16x32_bf16(pa, vb, acc2, 0, 0, 0);
        }
#pragma unroll
        for (int rg = 0; rg < 4; ++rg)
            o_prt[kh * 512 + (kg * 4 + rg) * 32 + ct * 16 + r16] = acc2[rg];
    }
    __syncthreads();

    // ---- combine halves, normalize, write (verified output mapping) ----
    {
        const int d0 = jj * 2;
        const float inv = 1.0f / rowsum[i];
        const float o0 = (o_prt[i * 32 + d0]     + o_prt[512 + i * 32 + d0])     * inv;
        const float o1 = (o_prt[i * 32 + d0 + 1] + o_prt[512 + i * 32 + d0 + 1]) * inv;
        const u32 ob = (u32)f2b(o0) | ((u32)f2b(o1) << 16);
        *(u32*)(O + (size_t)(s * 16 + i) * 256 + h * 32 + d0) = ob;
    }
}

// ---------- residual add + LayerNorm; writes fp32 X and bf16 Xb ------------
__global__ LB void k_add_ln(float* __restrict__ X, u16* __restrict__ Xb,
                            const float* __restrict__ D,
                            const float* __restrict__ w, const float* __restrict__ b)
{
    const int row  = blockIdx.x * 4 + (threadIdx.x >> 6);
    const int lane = threadIdx.x & 63;
    float4 x = ((const float4*)(X + (size_t)row * 256))[lane];
    const float4 d = ((const float4*)(D + (size_t)row * 256))[lane];
    x.x += d.x; x.y += d.y; x.z += d.z; x.w += d.w;
    float s = x.x + x.y + x.z + x.w;
#pragma unroll
    for (int m = 1; m < 64; m <<= 1) s += __shfl_xor(s, m);
    const float mu = s * (1.0f / 256.0f);
    const float4 c = make_float4(x.x - mu, x.y - mu, x.z - mu, x.w - mu);
    float q = c.x * c.x + c.y * c.y + c.z * c.z + c.w * c.w;
#pragma unroll
    for (int m = 1; m < 64; m <<= 1) q += __shfl_xor(q, m);
    const float inv = 1.0f / sqrtf(q * (1.0f / 256.0f) + 1e-5f);
    const float4 w4 = ((const float4*)w)[lane];
    const float4 b4 = ((const float4*)b)[lane];
    float4 o;
    o.x = c.x * inv * w4.x + b4.x;
    o.y = c.y * inv * w4.y + b4.y;
    o.z = c.z * inv * w4.z + b4.z;
    o.w = c.w * inv * w4.w + b4.w;
    ((float4*)(X + (size_t)row * 256))[lane] = o;
    ushort4 ob;
    ob.x = f2b(o.x); ob.y = f2b(o.y); ob.z = f2b(o.z); ob.w = f2b(o.w);
    ((ushort4*)(Xb + (size_t)row * 256))[lane] = ob;
}

// ---------- output head: (8192,256) @ (4,256)^T + b ------------------------
__global__ LB void k_out(const float* __restrict__ X, const float* __restrict__ W,
                         const float* __restrict__ bias, float* __restrict__ O)
{
    __shared__ float w_s[4][260];
    const int t = threadIdx.x;
    for (int e = t; e < 1024; e += 256) w_s[e >> 8][e & 255] = W[e];
    __syncthreads();
    const int row = blockIdx.x * 64 + (t >> 2);
    const int j = t & 3;
    const float4* xr = (const float4*)(X + (size_t)row * 256);
    float acc = 0.0f;
#pragma unroll
    for (int k4 = 0; k4 < 64; ++k4) {
        const float4 x = xr[k4];
        acc += x.x * w_s[j][k4 * 4]     + x.y * w_s[j][k4 * 4 + 1]
             + x.z * w_s[j][k4 * 4 + 2] + x.w * w_s[j][k4 * 4 + 3];
    }
    O[(size_t)row * 4 + j] = acc + bias[j];
}

// ---------------------------------------------------------------------------
extern "C" void kernel_launch(void* const* d_in, const int* in_sizes, int n_in,
                              void* d_out, int out_size, void* d_ws, size_t ws_size,
                              hipStream_t stream)
{
    const float* img          = (const float*)d_in[0];
    const float* kps          = (const float*)d_in[1];
    const unsigned char* vmsk = (const unsigned char*)d_in[2];
    const float* proj_w       = (const float*)d_in[3];
    const float* proj_b       = (const float*)d_in[4];
    const float* query_embed  = (const float*)d_in[5];
    const float* self_qkv_w   = (const float*)d_in[6];
    const float* self_qkv_b   = (const float*)d_in[7];
    const float* self_out_w   = (const float*)d_in[8];
    const float* self_out_b   = (const float*)d_in[9];
    const float* cross_qkv_w  = (const float*)d_in[10];
    const float* cross_qkv_b  = (const float*)d_in[11];
    const float* cross_out_w  = (const float*)d_in[12];
    const float* cross_out_b  = (const float*)d_in[13];
    const float* ffn1_w       = (const float*)d_in[14];
    const float* ffn1_b       = (const float*)d_in[15];
    const float* ffn2_w       = (const float*)d_in[16];
    const float* ffn2_b       = (const float*)d_in[17];
    const float* ln1_w        = (const float*)d_in[18];
    const float* ln1_b        = (const float*)d_in[19];
    const float* ln2_w        = (const float*)d_in[20];
    const float* ln2_b        = (const float*)d_in[21];
    const float* ln3_w        = (const float*)d_in[22];
    const float* ln3_b        = (const float*)d_in[23];
    const float* out_w        = (const float*)d_in[24];
    const float* out_b        = (const float*)d_in[25];
    float* out = (float*)d_out;

    // ---- workspace layout ----
    char* W8 = (char*)d_ws;
    size_t off = 0;
    auto alloc = [&](size_t bytes) { void* p = W8 + off; off += (bytes + 255) & ~(size_t)255; return p; };
    float* tgt   = (float*)alloc(2097152 * 4);
    float* Qbuf  = (float*)alloc(2097152 * 4);   // low half reused as bf16 Qb
    float* Pbuf  = (float*)alloc(2097152 * 4);
    float* Sbuf  = (float*)alloc(6291456 * 4);
    float* ckv   = (float*)alloc(3 * 512 * 4);
    u16* imgTb   = (u16*)alloc(2097152 * 2);
    u16* imgPb   = (u16*)alloc(2097152 * 2);
    u16* KVb     = (u16*)alloc(4194304 * 2);
    u16* tgtb    = (u16*)alloc(2097152 * 2);
    u16* Abuf    = (u16*)alloc(2097152 * 2);
    u16* Hbuf    = (u16*)alloc(8388608 * 2);
    u16* wAll    = (u16*)alloc(3211264 * 2);
    int* valid   = (int*)alloc(512 * 4);
    u16* Qb = (u16*)Qbuf;

    u16* wProj = wAll;             // 65536
    u16* wSQKV = wProj + 65536;    // 3*768*256
    u16* wSOut = wSQKV + 589824;   // 3*256*256
    u16* wCQKV = wSOut + 196608;   // 3*768*256
    u16* wCOut = wCQKV + 589824;   // 3*256*256
    u16* wF1   = wCOut + 196608;   // 3*1024*256
    u16* wF2   = wF1 + 786432;     // 3*256*1024

    k_prep<<<4, 256, 0, stream>>>(vmsk, valid, proj_b, cross_qkv_w, cross_qkv_b, ckv);
    k_wconv<<<12544, 256, 0, stream>>>(proj_w, self_qkv_w, self_out_w, cross_qkv_w,
                                       cross_out_w, ffn1_w, ffn2_w, wAll);
    k_transpose<<<dim3(64, 4, 2), 256, 0, stream>>>(img, imgTb);
    gemm_mfma<64><<<dim3(2, 128), 256, 0, stream>>>(imgTb, wProj, nullptr,
                                                    nullptr, imgPb, 8192, 256, 256, 0);
    k_init_tgt<<<8192, 256, 0, stream>>>(tgt, tgtb, query_embed);

    for (int l = 0; l < 3; ++l) {
        // ---- self attention ----
        gemm_mfma<128><<<dim3(6, 64), 256, 0, stream>>>(tgtb, wSQKV + (size_t)l * 196608,
            self_qkv_b + (size_t)l * 768, Sbuf, nullptr, 8192, 768, 256, 0);
        k_self_attn<<<4096, 256, 0, stream>>>(Sbuf, Abuf);
        gemm_mfma<64><<<dim3(2, 128), 256, 0, stream>>>(Abuf, wSOut + (size_t)l * 65536,
            self_out_b + (size_t)l * 256, Pbuf, nullptr, 8192, 256, 256, 0);
        k_add_ln<<<2048, 256, 0, stream>>>(tgt, tgtb, Pbuf,
            ln1_w + (size_t)l * 256, ln1_b + (size_t)l * 256);

        // ---- cross attention ----
        gemm_mfma<64><<<dim3(2, 128), 256, 0, stream>>>(tgtb, wCQKV + (size_t)l * 196608,
            cross_qkv_b + (size_t)l * 768, nullptr, Qb, 8192, 256, 256, 0);
        gemm_mfma<128><<<dim3(4, 64), 256, 0, stream>>>(imgPb,
            wCQKV + (size_t)l * 196608 + 65536, nullptr,
            nullptr, KVb, 8192, 512, 256, 0);
        k_cross_attn<<<4096, 256, 0, stream>>>(Qb, KVb, ckv + (size_t)l * 512,
                                               valid, kps, Abuf);
        gemm_mfma<64><<<dim3(2, 128), 256, 0, stream>>>(Abuf, wCOut + (size_t)l * 65536,
            cross_out_b + (size_t)l * 256, Pbuf, nullptr, 8192, 256, 256, 0);
        k_add_ln<<<2048, 256, 0, stream>>>(tgt, tgtb, Pbuf,
            ln2_w + (size_t)l * 256, ln2_b + (size_t)l * 256);

        // ---- FFN ----
        gemm_mfma<128><<<dim3(8, 64), 256, 0, stream>>>(tgtb, wF1 + (size_t)l * 262144,
            ffn1_b + (size_t)l * 1024, nullptr, Hbuf, 8192, 1024, 256, 1);
        gemm_mfma<64><<<dim3(2, 128), 256, 0, stream>>>(Hbuf, wF2 + (size_t)l * 262144,
            ffn2_b + (size_t)l * 256, Pbuf, nullptr, 8192, 256, 1024, 0);
        k_add_ln<<<2048, 256, 0, stream>>>(tgt, tgtb, Pbuf,
            ln3_w + (size_t)l * 256, ln3_b + (size_t)l * 256);
    }

    k_out<<<128, 256, 0, stream>>>(tgt, out_w, out_b, out);
}